// Round 17
// baseline (5309.499 us; speedup 1.0000x reference)
//
#include <hip/hip_runtime.h>
#include <math.h>

#define NS 32768

static __device__ __forceinline__ float leakyf(float x){ return x >= 0.f ? x : 0.2f*x; }

// ---------------- weight transpose for dilated stack: wT[l][sg][j][cc][o] ----------------
__global__ void k_wtrans(const float* __restrict__ ws, const float* __restrict__ wg, float* __restrict__ wT)
{
    int idx = blockIdx.x*256 + threadIdx.x;
    const int total = 7*2*3*128*128;
    if (idx >= total) return;
    int o  = idx & 127;
    int cc = (idx >> 7) & 127;
    int j  = (idx >> 14) % 3;
    int sg = (idx / 49152) & 1;
    int l  = idx / 98304;
    const float* src = sg ? wg : ws;
    wT[idx] = src[((l*128 + o)*128 + cc)*3 + j];
}

// ---------------- stage-2 weight transpose: woT/wnT [l][c][o] ----------------
__global__ void k_wtrans2(const float* __restrict__ wo, const float* __restrict__ wn,
                          float* __restrict__ woT, float* __restrict__ wnT)
{
    int idx = blockIdx.x*256 + threadIdx.x;
    if (idx >= 7*128*128) return;
    int o = idx & 127;
    int c = (idx >> 7) & 127;
    int l = idx >> 14;
    woT[idx] = wo[(l*128 + o)*128 + c];
    wnT[idx] = wn[(l*128 + o)*128 + c];
}

// ---------------- conv_up weight transposes ----------------
__global__ void k_wtrans_up(const float* __restrict__ ecw, const float* __restrict__ tcw,
                            const float* __restrict__ tfw, float* __restrict__ wtu, float* __restrict__ wtf)
{
    int idx = blockIdx.x*256 + threadIdx.x;
    if (idx < 393216) {
        int o = idx & 127;
        int j = (idx >> 7) % 3;
        int c = (idx / 384) & 127;
        int ml = idx / 49152;
        const float* src = (ml < 4 ? ecw : tcw) + (ml & 3)*49152;
        wtu[idx] = src[(o*128 + c)*3 + j];
    }
    if (idx < 208896) {
        int ct = idx % 544;
        int j = (idx / 544) % 3;
        int c = idx / 1632;
        wtf[idx] = (ct < 514) ? tfw[(ct*128 + c)*3 + j] : 0.f;
    }
}

// ---------------- front conv: n[b,c,t] = sum_k x[b, t+k-256] * fbw[c,k] ----------------
__global__ __launch_bounds__(512) void k_front(const float* __restrict__ x, const float* __restrict__ fbw,
                                               float* __restrict__ n0)
{
    int b = blockIdx.y;
    int t0 = blockIdx.x * 64;
    int tid = threadIdx.x;
    int t = tid & 63, og = tid >> 6;
    __shared__ float xs[576];
    __shared__ float4 wl[2048];
    for (int i = tid; i < 575; i += 512) {
        int p = t0 + i - 256;
        xs[i] = ((unsigned)p < NS) ? x[b*NS + p] : 0.f;
    }
    float s[16];
    #pragma unroll
    for (int i = 0; i < 16; ++i) s[i] = 0.f;
    for (int kc = 0; kc < 8; ++kc) {
        __syncthreads();
        for (int i = tid; i < 2048; i += 512) {
            int c = i >> 4, k4 = i & 15;
            wl[i] = *(const float4*)(fbw + c*512 + kc*64 + k4*4);
        }
        __syncthreads();
        for (int k4 = 0; k4 < 16; ++k4) {
            int base = t + kc*64 + k4*4;
            float xv0 = xs[base+0], xv1 = xs[base+1], xv2 = xs[base+2], xv3 = xs[base+3];
            #pragma unroll
            for (int i = 0; i < 16; ++i) {
                float4 w = wl[(og*16 + i)*16 + k4];
                s[i] += w.x*xv0 + w.y*xv1 + w.z*xv2 + w.w*xv3;
            }
        }
    }
    #pragma unroll
    for (int i = 0; i < 16; ++i)
        n0[(size_t)(b*128 + og*16 + i)*NS + t0 + t] = s[i];
}

// ---------------- one dilated gated layer: 4 contiguous t-points/thread, 8 o/thread ----------------
__global__ __launch_bounds__(512) void k_layer(const float* __restrict__ nin, float* __restrict__ nout,
        float* __restrict__ acc, const float* __restrict__ wTl,
        const float* __restrict__ bs, const float* __restrict__ bg,
        const float* __restrict__ woTl, const float* __restrict__ bo,
        const float* __restrict__ wnTl, const float* __restrict__ bn,
        int d, int first)
{
    __shared__ float pool[20480]; // 80 KB
    int b = blockIdx.y;
    int t0 = blockIdx.x * 128;
    int tid = threadIdx.x;
    int l = tid & 31, og = tid >> 5;   // 16 o-groups of 8
    int o0 = og * 8;
    int t4 = l * 4;
    const float* nb = nin + (size_t)b*128*NS;
    const float4* wq = (const float4*)wTl;

    int sci = tid >> 5;
    int st4 = (tid & 31) * 4;
    int wsgA = 0,              wccA = (tid >> 5) & 15,        wo4A = tid & 31;
    int wsgB = (tid+512) >> 9, wccB = ((tid+512) >> 5) & 15,  wo4B = (tid+512) & 31;

    float4 sreg, wr0, wr1;
    {
        int p = t0 + st4 - d;
        const float* bp = nb + (size_t)sci*NS;
        float v0 = ((unsigned)(p+0) < NS) ? bp[p+0] : 0.f;
        float v1 = ((unsigned)(p+1) < NS) ? bp[p+1] : 0.f;
        float v2 = ((unsigned)(p+2) < NS) ? bp[p+2] : 0.f;
        float v3 = ((unsigned)(p+3) < NS) ? bp[p+3] : 0.f;
        sreg = make_float4(v0,v1,v2,v3);
        wr0 = wq[((wsgA*3 + 0)*128 + wccA)*32 + wo4A];
        wr1 = wq[((wsgB*3 + 0)*128 + wccB)*32 + wo4B];
    }

    float sA[8], sB[8], sC[8], sD[8], gA[8], gB[8], gC[8], gD[8];
    #pragma unroll
    for (int i = 0; i < 8; ++i) {
        float bv = bs[o0+i], gv = bg[o0+i];
        sA[i]=bv; sB[i]=bv; sC[i]=bv; sD[i]=bv;
        gA[i]=gv; gB[i]=gv; gC[i]=gv; gD[i]=gv;
    }

    #pragma unroll 1
    for (int cnt = 0; cnt < 24; ++cnt) {
        int cur = cnt & 1;
        ((float4*)(pool + cur*2048))[tid] = sreg;
        {
            float4* wb = (float4*)(pool + 4096 + cur*4096);
            wb[tid] = wr0; wb[tid + 512] = wr1;
        }
        if (cnt < 23) {
            int nxt = cnt + 1;
            int jn = nxt >> 3, cbn = nxt & 7;
            int p = t0 + st4 + (jn-1)*d;
            const float* bp = nb + (size_t)(cbn*16 + sci)*NS;
            float v0 = ((unsigned)(p+0) < NS) ? bp[p+0] : 0.f;
            float v1 = ((unsigned)(p+1) < NS) ? bp[p+1] : 0.f;
            float v2 = ((unsigned)(p+2) < NS) ? bp[p+2] : 0.f;
            float v3 = ((unsigned)(p+3) < NS) ? bp[p+3] : 0.f;
            sreg = make_float4(v0,v1,v2,v3);
            wr0 = wq[((wsgA*3 + jn)*128 + cbn*16 + wccA)*32 + wo4A];
            wr1 = wq[((wsgB*3 + jn)*128 + cbn*16 + wccB)*32 + wo4B];
        }
        __syncthreads();
        const float* sb = pool + cur*2048;
        const float4* wS4 = (const float4*)(pool + 4096 + cur*4096);
        const float4* wG4 = wS4 + 512;
        for (int ccx = 0; ccx < 16; ++ccx) {
            float4 nv = *(const float4*)(sb + ccx*128 + t4);
            #pragma unroll
            for (int i4 = 0; i4 < 2; ++i4) {
                float4 wsv = wS4[ccx*32 + og*2 + i4];
                float4 wgv = wG4[ccx*32 + og*2 + i4];
                int ib = i4*4;
#define ST1(CMP, OO) \
                sA[OO] += nv.x*wsv.CMP; sB[OO] += nv.y*wsv.CMP; sC[OO] += nv.z*wsv.CMP; sD[OO] += nv.w*wsv.CMP; \
                gA[OO] += nv.x*wgv.CMP; gB[OO] += nv.y*wgv.CMP; gC[OO] += nv.z*wgv.CMP; gD[OO] += nv.w*wgv.CMP;
                ST1(x, ib+0) ST1(y, ib+1) ST1(z, ib+2) ST1(w, ib+3)
#undef ST1
            }
        }
    }

    __syncthreads();
    #pragma unroll
    for (int i = 0; i < 8; ++i) {
        float h0 = tanhf(sA[i]) * (1.f/(1.f + __expf(-gA[i])));
        float h1 = tanhf(sB[i]) * (1.f/(1.f + __expf(-gB[i])));
        float h2 = tanhf(sC[i]) * (1.f/(1.f + __expf(-gC[i])));
        float h3 = tanhf(sD[i]) * (1.f/(1.f + __expf(-gD[i])));
        *(float4*)(pool + (o0+i)*128 + t4) = make_float4(h0,h1,h2,h3);
    }

    int aarm = tid >> 8, arest = tid & 255;
    int accx = arest >> 5, ao4 = arest & 31;
    float4 w2r;
    {
        const float4* src = (const float4*)(aarm ? wnTl : woTl);
        w2r = src[(0*8 + accx)*32 + ao4];
    }

    float aA[8], aB[8], aC[8], aD[8], nA[8], nB[8], nC[8], nD[8];
    #pragma unroll
    for (int i = 0; i < 8; ++i) { aA[i]=0.f;aB[i]=0.f;aC[i]=0.f;aD[i]=0.f;nA[i]=0.f;nB[i]=0.f;nC[i]=0.f;nD[i]=0.f; }

    #pragma unroll 1
    for (int cb2 = 0; cb2 < 16; ++cb2) {
        int cur = cb2 & 1;
        ((float4*)(pool + 16384 + cur*2048))[tid] = w2r;
        if (cb2 < 15) {
            const float4* src = (const float4*)(aarm ? wnTl : woTl);
            w2r = src[((cb2+1)*8 + accx)*32 + ao4];
        }
        __syncthreads();
        const float4* w2S = (const float4*)(pool + 16384 + cur*2048);
        const float4* w2N = w2S + 256;
        for (int ccx = 0; ccx < 8; ++ccx) {
            float4 hv = *(const float4*)(pool + (cb2*8 + ccx)*128 + t4);
            #pragma unroll
            for (int i4 = 0; i4 < 2; ++i4) {
                float4 wov = w2S[ccx*32 + og*2 + i4];
                float4 wnv = w2N[ccx*32 + og*2 + i4];
                int ib = i4*4;
#define ST2(CMP, OO) \
                aA[OO] += hv.x*wov.CMP; aB[OO] += hv.y*wov.CMP; aC[OO] += hv.z*wov.CMP; aD[OO] += hv.w*wov.CMP; \
                nA[OO] += hv.x*wnv.CMP; nB[OO] += hv.y*wnv.CMP; nC[OO] += hv.z*wnv.CMP; nD[OO] += hv.w*wnv.CMP;
                ST2(x, ib+0) ST2(y, ib+1) ST2(z, ib+2) ST2(w, ib+3)
#undef ST2
            }
        }
    }

    #pragma unroll
    for (int i = 0; i < 8; ++i) {
        int o = o0 + i;
        float bov = bo[o], bnv = bn[o];
        size_t gi = (size_t)(b*128 + o)*NS + t0 + t4;
        float4 av = first ? make_float4(0.f,0.f,0.f,0.f) : *(const float4*)(acc + gi);
        float4 nf = *(const float4*)(nin + gi);
        *(float4*)(acc + gi)  = make_float4(av.x + aA[i] + bov, av.y + aB[i] + bov,
                                            av.z + aC[i] + bov, av.w + aD[i] + bov);
        *(float4*)(nout + gi) = make_float4(nA[i] + bnv + nf.x, nB[i] + bnv + nf.y,
                                            nC[i] + bnv + nf.z, nD[i] + bnv + nf.w);
    }
}

// ---------------- norms^2 over channels ----------------
__global__ void k_norms(const float* __restrict__ xf, float* __restrict__ norms)
{
    int b = blockIdx.y;
    int t = blockIdx.x*256 + threadIdx.x;
    float a = 0.f;
    for (int c = 0; c < 128; ++c) {
        float v = xf[(size_t)(b*128 + c)*NS + t];
        a += v*v;
    }
    norms[b*NS + t] = a;
}

// ---------------- top-32 per batch (destroys norms) ----------------
__global__ __launch_bounds__(1024) void k_topk(float* __restrict__ norms, float* __restrict__ topv, int* __restrict__ topi)
{
    int b = blockIdx.x;
    int tid = threadIdx.x;
    __shared__ float rv[1024];
    __shared__ int   ri[1024];
    for (int it = 0; it < 32; ++it) {
        float best = -2.f; int bi = 0;
        for (int k = tid; k < NS; k += 1024) {
            float v = norms[b*NS + k];
            if (v > best) { best = v; bi = k; }
        }
        rv[tid] = best; ri[tid] = bi;
        __syncthreads();
        for (int off = 512; off > 0; off >>= 1) {
            if (tid < off) {
                float ov = rv[tid+off]; int oi = ri[tid+off];
                if (ov > rv[tid] || (ov == rv[tid] && oi < ri[tid])) { rv[tid] = ov; ri[tid] = oi; }
            }
            __syncthreads();
        }
        if (tid == 0) {
            topv[b*32 + it] = sqrtf(rv[0]);
            topi[b*32 + it] = ri[0];
            norms[b*NS + ri[0]] = -1.f;
        }
        __syncthreads();
    }
}

// ---------------- gather latents ----------------
__global__ void k_latents(const float* __restrict__ xf, const int* __restrict__ topi, float* __restrict__ lat)
{
    int ev = blockIdx.x; int c = threadIdx.x;
    int b = ev >> 5;
    int idx = topi[ev];
    lat[ev*128 + c] = xf[(size_t)(b*128 + c)*NS + idx];
}

// ---------------- agg = max over time ----------------
__global__ void k_aggmax(const float* __restrict__ xf, float* __restrict__ agg)
{
    int rc = blockIdx.x;
    int tid = threadIdx.x;
    __shared__ float red[256];
    float m = -3.4e38f;
    const float* row = xf + (size_t)rc*NS;
    for (int t = tid; t < NS; t += 256) m = fmaxf(m, row[t]);
    red[tid] = m; __syncthreads();
    for (int off = 128; off > 0; off >>= 1) {
        if (tid < off) red[tid] = fmaxf(red[tid], red[tid+off]);
        __syncthreads();
    }
    if (tid == 0) agg[rc] = red[0];
}

// ---------------- upsample layer for 512 threads ----------------
template<int L2, int NPASS>
__device__ __forceinline__ void up_layerS(const float* __restrict__ wbase, const float* __restrict__ bias,
                                          const float* __restrict__ inb, float* __restrict__ outb,
                                          float* __restrict__ wst, int tid)
{
    constexpr int Lin = L2/2;
    constexpr int OGC = 512/L2;
    constexpr int OR  = 128/NPASS;
    constexpr int NO  = OR/OGC;
    constexpr int LOG = (L2==16)?4:(L2==32)?5:(L2==64)?6:7;
    int p  = tid & (L2-1);
    int og = tid >> LOG;
    int o0 = og*NO;
    #pragma unroll 1
    for (int pass = 0; pass < NPASS; ++pass) {
        int obase = pass*OR;
        float acc[NO];
        #pragma unroll
        for (int k = 0; k < NO; ++k) acc[k] = 0.f;
        #pragma unroll 1
        for (int cc0 = 0; cc0 < 128; cc0 += 16) {
            __syncthreads();
            for (int k = tid; k < 16*3*OR; k += 512) {
                int ci = k / (3*OR); int rem = k - ci*(3*OR);
                int j = rem / OR; int oo = rem - j*OR;
                wst[k] = wbase[(cc0+ci)*384 + j*128 + obase + oo];
            }
            __syncthreads();
            #pragma unroll 1
            for (int ci = 0; ci < 16; ++ci) {
                int c = cc0 + ci;
                float xv[3];
                #pragma unroll
                for (int j = 0; j < 3; ++j) {
                    int iu = p + j - 1;
                    xv[j] = ((unsigned)iu < (unsigned)L2) ? inb[c*Lin + (iu>>1)] : 0.f;
                }
                #pragma unroll
                for (int j = 0; j < 3; ++j) {
                    const float4* w4 = (const float4*)(wst + ci*3*OR + j*OR + o0);
                    #pragma unroll
                    for (int q = 0; q < NO/4; ++q) {
                        float4 w = w4[q];
                        acc[q*4+0] += xv[j]*w.x; acc[q*4+1] += xv[j]*w.y;
                        acc[q*4+2] += xv[j]*w.z; acc[q*4+3] += xv[j]*w.w;
                    }
                }
            }
        }
        #pragma unroll
        for (int k = 0; k < NO; ++k)
            outb[(obase + o0 + k)*L2 + p] = leakyf(acc[k] + bias[obase + o0 + k]);
    }
}

// ---------------- fused conv_up: gridDim=(128 events, 2 modes), 512 threads ----------------
// tf-final weights read DIRECTLY from global with wave-uniform (readfirstlane) addresses
// -> scalar s_load path, zero LDS-pipe slots (r16: weight ds_reads were the bottleneck).
__global__ __launch_bounds__(512) void k_convup3(const float* __restrict__ lat,
    const float* __restrict__ elw, const float* __restrict__ elb, const float* __restrict__ ecb,
    const float* __restrict__ efw, const float* __restrict__ efb,
    const float* __restrict__ tlw, const float* __restrict__ tlb, const float* __restrict__ tcb,
    const float* __restrict__ tfb, const float* __restrict__ wtu, const float* __restrict__ wtf,
    float* __restrict__ envsq, float* __restrict__ tfT)
{
    __shared__ float pool[35008]; // 136.75 KB
    float* latv = pool;           // 128
    float* bufA = pool + 128;     // 4160
    float* bufB = pool + 4288;    // 8192
    float* bufC = pool + 12480;   // 16384
    float* wst  = pool + 28864;   // 6144
    int ev = blockIdx.x;
    int m  = blockIdx.y;
    int tid = threadIdx.x;
    const float* lw = m ? tlw : elw;
    const float* lb = m ? tlb : elb;
    const float* cb = m ? tcb : ecb;
    const float* wu = wtu + m*4*49152;
    if (tid < 128) latv[tid] = lat[ev*128 + tid];
    __syncthreads();
    for (int jj = tid; jj < 1024; jj += 512) {
        float a = lb[jj];
        const float4* w4 = (const float4*)(lw + jj*128);
        #pragma unroll 8
        for (int q = 0; q < 32; ++q) {
            float4 w = w4[q];
            a += w.x*latv[q*4] + w.y*latv[q*4+1] + w.z*latv[q*4+2] + w.w*latv[q*4+3];
        }
        bufA[(jj>>3)*8 + (jj&7)] = a;
    }
    up_layerS<16,1>(wu,        cb,     bufA, bufB, wst, tid);
    up_layerS<32,1>(wu+49152,  cb+128, bufB, bufA, wst, tid);
    up_layerS<64,2>(wu+98304,  cb+256, bufA, bufB, wst, tid);
    up_layerS<128,4>(wu+147456,cb+384, bufB, bufC, wst, tid);
    __syncthreads();
    int p = tid & 127, g = tid >> 7;
    if (m == 0) {
        float s = 0.f;
        #pragma unroll 1
        for (int c = g*32; c < g*32+32; ++c) {
            #pragma unroll
            for (int j = 0; j < 3; ++j) {
                int iu = p + j - 1;
                float xv = ((unsigned)iu < 128u) ? bufC[c*128 + iu] : 0.f;
                s += efw[c*3+j]*xv;
            }
        }
        wst[g*128 + p] = s;
        __syncthreads();
        if (g == 0) {
            float a = wst[p] + wst[128+p] + wst[256+p] + wst[384+p] + efb[0];
            envsq[ev*128 + p] = a*a;
        }
    } else {
        float* trb = bufA;
        int gu = __builtin_amdgcn_readfirstlane(g);   // wave-uniform ct-group
        #pragma unroll 1
        for (int ctb = 0; ctb < 17; ++ctb) {
            int ct0 = ctb*32;
            float acc[8];
            #pragma unroll
            for (int i = 0; i < 8; ++i) acc[i] = 0.f;
            const float* wbase = wtf + ct0 + gu*8;
            #pragma unroll 1
            for (int c = 0; c < 128; ++c) {
                float xm = (p >= 1)   ? bufC[c*128 + p - 1] : 0.f;
                float x0 = bufC[c*128 + p];
                float xp = (p < 127)  ? bufC[c*128 + p + 1] : 0.f;
                const float* wr = wbase + c*1632;
                #pragma unroll
                for (int j = 0; j < 3; ++j) {
                    float xv = (j == 0) ? xm : ((j == 1) ? x0 : xp);
                    float4 w0 = *(const float4*)(wr + j*544);
                    float4 w1 = *(const float4*)(wr + j*544 + 4);
                    acc[0] += xv*w0.x; acc[1] += xv*w0.y; acc[2] += xv*w0.z; acc[3] += xv*w0.w;
                    acc[4] += xv*w1.x; acc[5] += xv*w1.y; acc[6] += xv*w1.z; acc[7] += xv*w1.w;
                }
            }
            __syncthreads();      // prior trb readers done
            #pragma unroll
            for (int i = 0; i < 8; ++i) trb[(g*8 + i)*129 + p] = acc[i];
            __syncthreads();
            int ctl2 = tid & 31, pg = tid >> 5;
            #pragma unroll 1
            for (int ps = 0; ps < 8; ++ps) {
                int pp = ps*16 + pg;
                int ct = ct0 + ctl2;
                if (ct < 514)
                    tfT[(size_t)(ev*128 + pp)*514 + ct] = trb[ctl2*129 + pp] + tfb[ct];
            }
            __syncthreads();
        }
    }
}

// ---------------- impulse transfer lin_stack ----------------
__global__ __launch_bounds__(128) void k_itf(const float* __restrict__ lat,
    const float* __restrict__ iw, const float* __restrict__ ib,
    const float* __restrict__ iow, const float* __restrict__ iob,
    float* __restrict__ itf)
{
    int ev = blockIdx.x; int tid = threadIdx.x;
    __shared__ float xa[128], xb[128];
    xa[tid] = lat[ev*128 + tid];
    __syncthreads();
    float* src = xa; float* dst = xb;
    for (int l = 0; l < 3; ++l) {
        float a = ib[l*128 + tid];
        const float* wr = iw + (l*128 + tid)*128;
        for (int k = 0; k < 128; ++k) a += wr[k]*src[k];
        dst[tid] = leakyf(a);
        __syncthreads();
        float* tmp = src; src = dst; dst = tmp;
    }
    for (int o = tid; o < 514; o += 128) {
        float a = iob[o];
        const float* wr = iow + o*128;
        for (int k = 0; k < 128; ++k) a += wr[k]*src[k];
        itf[ev*514 + o] = a;
    }
}

// ---------------- room/mix lin_stacks + softmax ----------------
__global__ __launch_bounds__(128) void k_roommix(const float* __restrict__ agg,
    const float* __restrict__ rw, const float* __restrict__ rb,
    const float* __restrict__ row_, const float* __restrict__ rob,
    const float* __restrict__ mw, const float* __restrict__ mb,
    const float* __restrict__ mow, const float* __restrict__ mob,
    float* __restrict__ probs, float* __restrict__ mval)
{
    int b = blockIdx.x; int tid = threadIdx.x;
    __shared__ float xa[128], xb[128], rr[8];
    xa[tid] = agg[b*128 + tid];
    __syncthreads();
    float* src = xa; float* dst = xb;
    for (int l = 0; l < 3; ++l) {
        float a = rb[l*128 + tid];
        const float* wr = rw + (l*128 + tid)*128;
        for (int k = 0; k < 128; ++k) a += wr[k]*src[k];
        dst[tid] = leakyf(a);
        __syncthreads();
        float* tmp = src; src = dst; dst = tmp;
    }
    if (tid < 8) {
        float a = rob[tid];
        const float* wr = row_ + tid*128;
        for (int k = 0; k < 128; ++k) a += wr[k]*src[k];
        rr[tid] = a;
    }
    __syncthreads();
    if (tid == 0) {
        float m = rr[0];
        for (int j = 1; j < 8; ++j) m = fmaxf(m, rr[j]);
        float ssum = 0.f; float e[8];
        for (int j = 0; j < 8; ++j) { e[j] = __expf(rr[j]-m); ssum += e[j]; }
        for (int j = 0; j < 8; ++j) probs[b*8+j] = e[j]/ssum;
    }
    __syncthreads();
    xa[tid] = agg[b*128 + tid];
    __syncthreads();
    src = xa; dst = xb;
    for (int l = 0; l < 3; ++l) {
        float a = mb[l*128 + tid];
        const float* wr = mw + (l*128 + tid)*128;
        for (int k = 0; k < 128; ++k) a += wr[k]*src[k];
        dst[tid] = leakyf(a);
        __syncthreads();
        float* tmp = src; src = dst; dst = tmp;
    }
    if (tid == 0) {
        float a = mob[0];
        for (int k = 0; k < 128; ++k) a += mow[k]*src[k];
        mval[b] = a;
    }
}

// ---------------- ir = softmax(r) @ rooms ----------------
__global__ void k_ir(const float* __restrict__ probs, const float* __restrict__ rooms, float* __restrict__ ir)
{
    int b = blockIdx.y;
    int t = blockIdx.x*256 + threadIdx.x;
    float a = 0.f;
    for (int j = 0; j < 8; ++j) a += probs[b*8+j]*rooms[j*NS + t];
    ir[b*NS + t] = a;
}

// ---------------- prep: full Hermitian spectra in bit-reversed order ----------------
__global__ void k_tfprep(const float* __restrict__ tfT, float2* __restrict__ Tscr)
{
    int f = blockIdx.x, ev = blockIdx.y;
    const float* tp = tfT + ((size_t)(ev*128 + f))*514;
    float2* dst = Tscr + ((size_t)(ev*128 + f))*512;
    int t = threadIdx.x;
    #pragma unroll
    for (int h = 0; h < 2; ++h) {
        int slot = t + h*256;
        int pos = (int)(__brev((unsigned)slot) >> 23);
        float2 H;
        if (pos == 0)        H = make_float2(tp[0], 0.f);
        else if (pos == 256) H = make_float2(tp[512], 0.f);
        else if (pos < 256)  H = make_float2(tp[2*pos], tp[2*pos+1]);
        else { int q = 512 - pos; H = make_float2(tp[2*q], -tp[2*q+1]); }
        dst[slot] = H;
    }
}

__global__ void k_itfprep(const float* __restrict__ itf, float2* __restrict__ iscr)
{
    int ev = blockIdx.x;
    const float* tp = itf + (size_t)ev*514;
    float2* dst = iscr + (size_t)ev*512;
    int t = threadIdx.x;
    #pragma unroll
    for (int h = 0; h < 2; ++h) {
        int slot = t + h*256;
        int pos = (int)(__brev((unsigned)slot) >> 23);
        float2 H;
        if (pos == 0)        H = make_float2(tp[0], 0.f);
        else if (pos == 256) H = make_float2(tp[512], 0.f);
        else if (pos < 256)  H = make_float2(tp[2*pos], tp[2*pos+1]);
        else { int q = 512 - pos; H = make_float2(tp[2*q], -tp[2*q+1]); }
        dst[slot] = H;
    }
}

// ---------------- 512-pt real-in filter: DIF fwd (no reorder) * Tscr -> DIT inv ----------------
__device__ __forceinline__ void fft_filt(float nx0, float nx1,
    const float2* __restrict__ Tf,
    float* __restrict__ re, float* __restrict__ im,
    const float* __restrict__ twr, const float* __restrict__ twi,
    int t, float& out0, float& out1)
{
    int w = t >> 6, l = t & 63;
    int c0 = (w << 7) + l;
    {
        float d = nx0 - nx1;
        re[t] = nx0 + nx1; im[t] = 0.f;
        re[t+256] = d * twr[t]; im[t+256] = d * twi[t];
    }
    __syncthreads();
    {
        int i = (t & 127) + ((t >> 7) << 8);
        int j = i & 127;
        float wr = twr[j*2], wi = twi[j*2];
        float ur = re[i], ui = im[i], vr = re[i+128], vi = im[i+128];
        re[i] = ur + vr; im[i] = ui + vi;
        float dr = ur - vr, di = ui - vi;
        re[i+128] = dr*wr - di*wi; im[i+128] = dr*wi + di*wr;
    }
    __syncthreads();
    float a0r = re[c0], a0i = im[c0], a1r = re[c0+64], a1i = im[c0+64];
    {
        float wr = twr[l*4], wi = twi[l*4];
        float ur = a0r, ui = a0i;
        a0r = ur + a1r; a0i = ui + a1i;
        float dr = ur - a1r, di = ui - a1i;
        a1r = dr*wr - di*wi; a1i = dr*wi + di*wr;
    }
#define DIFS(S, TS) { \
        int j = l & (S-1); float wr = twr[j*TS], wi = twi[j*TS]; \
        int up = l & S; \
        float o0r = __shfl_xor(a0r, S, 64), o0i = __shfl_xor(a0i, S, 64); \
        float o1r = __shfl_xor(a1r, S, 64), o1i = __shfl_xor(a1i, S, 64); \
        if (up) { float dr = o0r - a0r, di = o0i - a0i; a0r = dr*wr - di*wi; a0i = dr*wi + di*wr; \
                  float er = o1r - a1r, ei = o1i - a1i; a1r = er*wr - ei*wi; a1i = er*wi + ei*wr; } \
        else    { a0r += o0r; a0i += o0i; a1r += o1r; a1i += o1i; } }
    DIFS(32, 8) DIFS(16, 16) DIFS(8, 32) DIFS(4, 64) DIFS(2, 128) DIFS(1, 256)
#undef DIFS
    {
        float2 T0 = Tf[c0];
        float2 T1 = Tf[c0+64];
        float r = a0r*T0.x - a0i*T0.y; a0i = a0r*T0.y + a0i*T0.x; a0r = r;
        r = a1r*T1.x - a1i*T1.y; a1i = a1r*T1.y + a1i*T1.x; a1r = r;
    }
#define DITS(S, TS) { \
        int j = l & (S-1); float wr = twr[j*TS], wi = -twi[j*TS]; \
        int up = l & S; \
        if (up) { float r = a0r*wr - a0i*wi; a0i = a0r*wi + a0i*wr; a0r = r; \
                  r = a1r*wr - a1i*wi; a1i = a1r*wi + a1i*wr; a1r = r; } \
        float o0r = __shfl_xor(a0r, S, 64), o0i = __shfl_xor(a0i, S, 64); \
        float o1r = __shfl_xor(a1r, S, 64), o1i = __shfl_xor(a1i, S, 64); \
        if (up) { a0r = o0r - a0r; a0i = o0i - a0i; a1r = o1r - a1r; a1i = o1i - a1i; } \
        else    { a0r += o0r; a0i += o0i; a1r += o1r; a1i += o1i; } }
    DITS(1, 256) DITS(2, 128) DITS(4, 64) DITS(8, 32) DITS(16, 16) DITS(32, 8)
#undef DITS
    {
        float wr = twr[l*4], wi = -twi[l*4];
        float vr = a1r*wr - a1i*wi, vi = a1r*wi + a1i*wr;
        a1r = a0r - vr; a1i = a0i - vi;
        a0r += vr; a0i += vi;
    }
    __syncthreads();
    re[c0] = a0r; im[c0] = a0i; re[c0+64] = a1r; im[c0+64] = a1i;
    __syncthreads();
    {
        int i = (t & 127) + ((t >> 7) << 8);
        int j = i & 127;
        float wr = twr[j*2], wi = -twi[j*2];
        float ur = re[i], ui = im[i];
        float br = re[i+128], bi = im[i+128];
        float vr = br*wr - bi*wi, vi = br*wi + bi*wr;
        re[i] = ur + vr; im[i] = ui + vi;
        re[i+128] = ur - vr; im[i+128] = ui - vi;
    }
    __syncthreads();
    {
        float wr = twr[t], wi = -twi[t];
        float ur = re[t];
        float br = re[t+256], bi = im[t+256];
        float vr = br*wr - bi*wi;
        out0 = ur + vr;
        out1 = ur - vr;
    }
}

// ---------------- per-event scan with shuffle-FFT (5 barriers/frame) ----------------
__global__ __launch_bounds__(256) void k_event(const float2* __restrict__ Tscr, const float2* __restrict__ itfscr,
    const float* __restrict__ envsq, const float* __restrict__ noise, float* __restrict__ atoms)
{
    int ev = blockIdx.x; int t = threadIdx.x;
    __shared__ float twr[256], twi[256], re[512], im[512], envl[128];
    if (t < 128) envl[t] = envsq[ev*128 + t];
    {
        float ang = -6.283185307179586f * (float)t / 512.0f;
        float si, co;
        sincosf(ang, &si, &co);
        twr[t] = co; twi[t] = si;
    }
    float ham0 = 0.54f - 0.46f*cosf(6.283185307179586f*(float)t/512.0f);
    float ham1 = 0.54f - 0.46f*cosf(6.283185307179586f*(float)(t+256)/512.0f);
    __syncthreads();
    float imp0, imp1;
    fft_filt(noise[t], noise[t+256], itfscr + (size_t)ev*512, re, im, twr, twi, t, imp0, imp1);
    const float inv512 = 1.f/512.f;
    imp0 *= inv512; imp1 *= inv512;
    float carry0 = 0.f, carry1 = 0.f, accv = 0.f;
    #pragma unroll 1
    for (int f = 0; f < 128; ++f) {
        float e0, e1;
        {
            int tg = f*256 + t;
            float srcp = ((float)tg + 0.5f)*(1.0f/256.0f) - 0.5f;
            srcp = fminf(fmaxf(srcp, 0.f), 127.f);
            int i0 = (int)srcp; float fr = srcp - (float)i0;
            int i1 = i0 + 1; if (i1 > 127) i1 = 127;
            e0 = envl[i0]*(1.f-fr) + envl[i1]*fr;
        }
        {
            int tg = f*256 + 256 + t;
            e1 = 0.f;
            if (tg < NS) {
                float srcp = ((float)tg + 0.5f)*(1.0f/256.0f) - 0.5f;
                srcp = fminf(fmaxf(srcp, 0.f), 127.f);
                int i0 = (int)srcp; float fr = srcp - (float)i0;
                int i1 = i0 + 1; if (i1 > 127) i1 = 127;
                e1 = envl[i0]*(1.f-fr) + envl[i1]*fr;
            }
        }
        float nx0 = imp0*e0 + carry0;
        float nx1 = imp1*e1 + carry1;
        float o0, o1;
        fft_filt(nx0, nx1, Tscr + ((size_t)(ev*128 + f))*512, re, im, twr, twi, t, o0, o1);
        o0 *= inv512 * ham0;
        o1 *= inv512 * ham1;
        atoms[(size_t)ev*NS + f*256 + t] = o0 + accv;
        accv = o1; carry0 = o0; carry1 = o1;
    }
}

// ---------------- final = sum_a values[a]*atoms[a, t-idx[a]] ----------------
__global__ void k_gather(const float* __restrict__ atoms, const float* __restrict__ topv,
                         const int* __restrict__ topi, float* __restrict__ fin)
{
    int b = blockIdx.y;
    int t = blockIdx.x*256 + threadIdx.x;
    float s = 0.f;
    for (int a = 0; a < 32; ++a) {
        int ii = topi[b*32 + a];
        if (ii <= t) s += topv[b*32 + a] * atoms[(size_t)(b*32 + a)*NS + (t - ii)];
    }
    fin[b*NS + t] = s;
}

// ---------------- wet partials ----------------
__global__ __launch_bounds__(256) void k_wetpart(const float* __restrict__ fin, const float* __restrict__ ir,
                                                 float* __restrict__ wetp)
{
    int t0 = blockIdx.x*256;
    int by = blockIdx.y;
    int b = by >> 3, cg = by & 7;
    int tid = threadIdx.x;
    __shared__ float fs[256];
    __shared__ float irw[512];
    float wet = 0.f;
    int nch = t0/256 + 1;
    #pragma unroll 1
    for (int q = cg; q < nch; q += 8) {
        int c0 = q*256;
        __syncthreads();
        fs[tid] = fin[b*NS + c0 + tid];
        int dmin = t0 - c0 - 255;
        for (int qq = tid; qq < 511; qq += 256) {
            int dd = dmin + qq;
            irw[qq] = ((unsigned)dd < NS) ? ir[b*NS + dd] : 0.f;
        }
        __syncthreads();
        if (c0 < t0) {
            #pragma unroll 8
            for (int k = 0; k < 256; ++k) wet += fs[k]*irw[tid + 255 - k];
        } else {
            for (int k = 0; k <= tid; ++k) wet += fs[k]*irw[tid + 255 - k];
        }
    }
    wetp[(size_t)by*NS + t0 + tid] = wet;
}

// ---------------- out = m*sum(wet parts) + fin*(1-m) ----------------
__global__ __launch_bounds__(256) void k_wetsum(const float* __restrict__ fin, const float* __restrict__ wetp,
                                                const float* __restrict__ mval, float* __restrict__ out)
{
    int b = blockIdx.y;
    int t = blockIdx.x*256 + threadIdx.x;
    float w = 0.f;
    #pragma unroll
    for (int cg = 0; cg < 8; ++cg) w += wetp[(size_t)(b*8+cg)*NS + t];
    float m = mval[b];
    float fv = fin[b*NS + t];
    out[b*NS + t] = m*w + fv*(1.f - m);
}

extern "C" void kernel_launch(void* const* d_in, const int* in_sizes, int n_in,
                              void* d_out, int out_size, void* d_ws, size_t ws_size,
                              hipStream_t stream)
{
    (void)in_sizes; (void)n_in; (void)out_size; (void)ws_size;
    const float* x    = (const float*)d_in[0];
    const float* fbw  = (const float*)d_in[1];
    const float* dsw  = (const float*)d_in[2];
    const float* dsb  = (const float*)d_in[3];
    const float* dgw  = (const float*)d_in[4];
    const float* dgb  = (const float*)d_in[5];
    const float* dow  = (const float*)d_in[6];
    const float* dob  = (const float*)d_in[7];
    const float* dnw  = (const float*)d_in[8];
    const float* dnb  = (const float*)d_in[9];
    const float* elw  = (const float*)d_in[10];
    const float* elb  = (const float*)d_in[11];
    const float* ecw  = (const float*)d_in[12];
    const float* ecb  = (const float*)d_in[13];
    const float* efw  = (const float*)d_in[14];
    const float* efb  = (const float*)d_in[15];
    const float* tlw  = (const float*)d_in[16];
    const float* tlb  = (const float*)d_in[17];
    const float* tcw  = (const float*)d_in[18];
    const float* tcb  = (const float*)d_in[19];
    const float* tfw  = (const float*)d_in[20];
    const float* tfb  = (const float*)d_in[21];
    const float* iw   = (const float*)d_in[22];
    const float* ib   = (const float*)d_in[23];
    const float* iow  = (const float*)d_in[24];
    const float* iob  = (const float*)d_in[25];
    const float* rw   = (const float*)d_in[26];
    const float* rb   = (const float*)d_in[27];
    const float* row_ = (const float*)d_in[28];
    const float* rob  = (const float*)d_in[29];
    const float* mw   = (const float*)d_in[30];
    const float* mb   = (const float*)d_in[31];
    const float* mow  = (const float*)d_in[32];
    const float* mob  = (const float*)d_in[33];
    const float* rooms= (const float*)d_in[34];
    const float* noise= (const float*)d_in[35];

    float* ws   = (float*)d_ws;
    float* n0   = ws;                       // 16,777,216
    float* n1   = ws + 16777216;            // 16,777,216
    float* accb = ws + 33554432;            // 16,777,216
    float* wT   = ws + 50331648;            // 1,376,256
    float* woT  = ws + 51707904;            // 114,688
    float* wnT  = ws + 51822592;            // 114,688
    float* envsq= ws + 51937280;            // 16,384
    float* lat  = ws + 51953664;            // 16,384
    float* itfb = ws + 51970048;            // 65,792
    float* norms= ws + 52035840;            // 131,072
    float* topv = ws + 52166912;            // 128
    int*   topi = (int*)(ws + 52167040);    // 128
    float* agg  = ws + 52167168;            // 512
    float* probs= ws + 52167680;            // 32
    float* mval = ws + 52167712;            // 32
    float* irb  = ws + 52167744;            // 131,072
    float* fin  = ws + 52298816;            // 131,072
    float* tfT  = n0;                        // reuse after dilated stack is done
    float* atoms= n0 + 8421376;              // reuse
    float* wetp = n0 + 12615680;             // 1,048,576
    float* wtu  = n1;                        // 393,216  (dead after convup3)
    float* wtf  = n1 + 393216;               // 208,896  (dead after convup3)
    float2* Tscr   = (float2*)n1;            // 128*128*512 float2 (overwrites n1 after convup3)
    float2* itfscr = (float2*)accb;          // (accb dead after aggmax/latents)

    float* out = (float*)d_out;

    k_wtrans<<<dim3((1376256+255)/256), dim3(256), 0, stream>>>(dsw, dgw, wT);
    k_wtrans2<<<dim3((114688+255)/256), dim3(256), 0, stream>>>(dow, dnw, woT, wnT);
    k_front<<<dim3(512,4), dim3(512), 0, stream>>>(x, fbw, n0);

    const int dil[7] = {1,3,9,27,81,243,1};
    float* cin = n0; float* cout = n1;
    for (int l = 0; l < 7; ++l) {
        k_layer<<<dim3(256,4), dim3(512), 0, stream>>>(
            cin, cout, accb, wT + l*98304,
            dsb + l*128, dgb + l*128,
            woT + l*16384, dob + l*128,
            wnT + l*16384, dnb + l*128,
            dil[l], l==0 ? 1 : 0);
        float* tmp = cin; cin = cout; cout = tmp;
    }
    k_norms<<<dim3(128,4), dim3(256), 0, stream>>>(accb, norms);
    k_topk<<<dim3(4), dim3(1024), 0, stream>>>(norms, topv, topi);
    k_latents<<<dim3(128), dim3(128), 0, stream>>>(accb, topi, lat);
    k_aggmax<<<dim3(512), dim3(256), 0, stream>>>(accb, agg);
    k_wtrans_up<<<dim3(1536), dim3(256), 0, stream>>>(ecw, tcw, tfw, wtu, wtf);
    k_convup3<<<dim3(128,2), dim3(512), 0, stream>>>(lat, elw, elb, ecb, efw, efb,
                                                     tlw, tlb, tcb, tfb, wtu, wtf, envsq, tfT);
    k_itf<<<dim3(128), dim3(128), 0, stream>>>(lat, iw, ib, iow, iob, itfb);
    k_roommix<<<dim3(4), dim3(128), 0, stream>>>(agg, rw, rb, row_, rob, mw, mb, mow, mob, probs, mval);
    k_ir<<<dim3(128,4), dim3(256), 0, stream>>>(probs, rooms, irb);
    k_tfprep<<<dim3(128,128), dim3(256), 0, stream>>>(tfT, Tscr);
    k_itfprep<<<dim3(128), dim3(256), 0, stream>>>(itfb, itfscr);
    k_event<<<dim3(128), dim3(256), 0, stream>>>(Tscr, itfscr, envsq, noise, atoms);
    k_gather<<<dim3(128,4), dim3(256), 0, stream>>>(atoms, topv, topi, fin);
    k_wetpart<<<dim3(128,32), dim3(256), 0, stream>>>(fin, irb, wetp);
    k_wetsum<<<dim3(128,4), dim3(256), 0, stream>>>(fin, wetp, mval, out);
}

// Round 18
// 4999.773 us; speedup vs baseline: 1.0619x; 1.0619x over previous
//
#include <hip/hip_runtime.h>
#include <math.h>

#define NS 32768

static __device__ __forceinline__ float leakyf(float x){ return x >= 0.f ? x : 0.2f*x; }

// ---------------- weight transpose for dilated stack: wT[l][sg][j][cc][o] ----------------
__global__ void k_wtrans(const float* __restrict__ ws, const float* __restrict__ wg, float* __restrict__ wT)
{
    int idx = blockIdx.x*256 + threadIdx.x;
    const int total = 7*2*3*128*128;
    if (idx >= total) return;
    int o  = idx & 127;
    int cc = (idx >> 7) & 127;
    int j  = (idx >> 14) % 3;
    int sg = (idx / 49152) & 1;
    int l  = idx / 98304;
    const float* src = sg ? wg : ws;
    wT[idx] = src[((l*128 + o)*128 + cc)*3 + j];
}

// ---------------- stage-2 weight transpose: woT/wnT [l][c][o] ----------------
__global__ void k_wtrans2(const float* __restrict__ wo, const float* __restrict__ wn,
                          float* __restrict__ woT, float* __restrict__ wnT)
{
    int idx = blockIdx.x*256 + threadIdx.x;
    if (idx >= 7*128*128) return;
    int o = idx & 127;
    int c = (idx >> 7) & 127;
    int l = idx >> 14;
    woT[idx] = wo[(l*128 + o)*128 + c];
    wnT[idx] = wn[(l*128 + o)*128 + c];
}

// ---------------- conv_up weight transposes ----------------
__global__ void k_wtrans_up(const float* __restrict__ ecw, const float* __restrict__ tcw,
                            const float* __restrict__ tfw, float* __restrict__ wtu, float* __restrict__ wtf)
{
    int idx = blockIdx.x*256 + threadIdx.x;
    if (idx < 393216) {
        int o = idx & 127;
        int j = (idx >> 7) % 3;
        int c = (idx / 384) & 127;
        int ml = idx / 49152;
        const float* src = (ml < 4 ? ecw : tcw) + (ml & 3)*49152;
        wtu[idx] = src[(o*128 + c)*3 + j];
    }
    if (idx < 208896) {
        int ct = idx % 544;
        int j = (idx / 544) % 3;
        int c = idx / 1632;
        wtf[idx] = (ct < 514) ? tfw[(ct*128 + c)*3 + j] : 0.f;
    }
}

// ---------------- front conv: n[b,c,t] = sum_k x[b, t+k-256] * fbw[c,k] ----------------
__global__ __launch_bounds__(512) void k_front(const float* __restrict__ x, const float* __restrict__ fbw,
                                               float* __restrict__ n0)
{
    int b = blockIdx.y;
    int t0 = blockIdx.x * 64;
    int tid = threadIdx.x;
    int t = tid & 63, og = tid >> 6;
    __shared__ float xs[576];
    __shared__ float4 wl[2048];
    for (int i = tid; i < 575; i += 512) {
        int p = t0 + i - 256;
        xs[i] = ((unsigned)p < NS) ? x[b*NS + p] : 0.f;
    }
    float s[16];
    #pragma unroll
    for (int i = 0; i < 16; ++i) s[i] = 0.f;
    for (int kc = 0; kc < 8; ++kc) {
        __syncthreads();
        for (int i = tid; i < 2048; i += 512) {
            int c = i >> 4, k4 = i & 15;
            wl[i] = *(const float4*)(fbw + c*512 + kc*64 + k4*4);
        }
        __syncthreads();
        for (int k4 = 0; k4 < 16; ++k4) {
            int base = t + kc*64 + k4*4;
            float xv0 = xs[base+0], xv1 = xs[base+1], xv2 = xs[base+2], xv3 = xs[base+3];
            #pragma unroll
            for (int i = 0; i < 16; ++i) {
                float4 w = wl[(og*16 + i)*16 + k4];
                s[i] += w.x*xv0 + w.y*xv1 + w.z*xv2 + w.w*xv3;
            }
        }
    }
    #pragma unroll
    for (int i = 0; i < 16; ++i)
        n0[(size_t)(b*128 + og*16 + i)*NS + t0 + t] = s[i];
}

// ---------------- one dilated gated layer: 4 contiguous t-points/thread, 8 o/thread ----------------
__global__ __launch_bounds__(512) void k_layer(const float* __restrict__ nin, float* __restrict__ nout,
        float* __restrict__ acc, const float* __restrict__ wTl,
        const float* __restrict__ bs, const float* __restrict__ bg,
        const float* __restrict__ woTl, const float* __restrict__ bo,
        const float* __restrict__ wnTl, const float* __restrict__ bn,
        int d, int first)
{
    __shared__ float pool[20480]; // 80 KB
    int b = blockIdx.y;
    int t0 = blockIdx.x * 128;
    int tid = threadIdx.x;
    int l = tid & 31, og = tid >> 5;   // 16 o-groups of 8
    int o0 = og * 8;
    int t4 = l * 4;
    const float* nb = nin + (size_t)b*128*NS;
    const float4* wq = (const float4*)wTl;

    int sci = tid >> 5;
    int st4 = (tid & 31) * 4;
    int wsgA = 0,              wccA = (tid >> 5) & 15,        wo4A = tid & 31;
    int wsgB = (tid+512) >> 9, wccB = ((tid+512) >> 5) & 15,  wo4B = (tid+512) & 31;

    float4 sreg, wr0, wr1;
    {
        int p = t0 + st4 - d;
        const float* bp = nb + (size_t)sci*NS;
        float v0 = ((unsigned)(p+0) < NS) ? bp[p+0] : 0.f;
        float v1 = ((unsigned)(p+1) < NS) ? bp[p+1] : 0.f;
        float v2 = ((unsigned)(p+2) < NS) ? bp[p+2] : 0.f;
        float v3 = ((unsigned)(p+3) < NS) ? bp[p+3] : 0.f;
        sreg = make_float4(v0,v1,v2,v3);
        wr0 = wq[((wsgA*3 + 0)*128 + wccA)*32 + wo4A];
        wr1 = wq[((wsgB*3 + 0)*128 + wccB)*32 + wo4B];
    }

    float sA[8], sB[8], sC[8], sD[8], gA[8], gB[8], gC[8], gD[8];
    #pragma unroll
    for (int i = 0; i < 8; ++i) {
        float bv = bs[o0+i], gv = bg[o0+i];
        sA[i]=bv; sB[i]=bv; sC[i]=bv; sD[i]=bv;
        gA[i]=gv; gB[i]=gv; gC[i]=gv; gD[i]=gv;
    }

    #pragma unroll 1
    for (int cnt = 0; cnt < 24; ++cnt) {
        int cur = cnt & 1;
        ((float4*)(pool + cur*2048))[tid] = sreg;
        {
            float4* wb = (float4*)(pool + 4096 + cur*4096);
            wb[tid] = wr0; wb[tid + 512] = wr1;
        }
        if (cnt < 23) {
            int nxt = cnt + 1;
            int jn = nxt >> 3, cbn = nxt & 7;
            int p = t0 + st4 + (jn-1)*d;
            const float* bp = nb + (size_t)(cbn*16 + sci)*NS;
            float v0 = ((unsigned)(p+0) < NS) ? bp[p+0] : 0.f;
            float v1 = ((unsigned)(p+1) < NS) ? bp[p+1] : 0.f;
            float v2 = ((unsigned)(p+2) < NS) ? bp[p+2] : 0.f;
            float v3 = ((unsigned)(p+3) < NS) ? bp[p+3] : 0.f;
            sreg = make_float4(v0,v1,v2,v3);
            wr0 = wq[((wsgA*3 + jn)*128 + cbn*16 + wccA)*32 + wo4A];
            wr1 = wq[((wsgB*3 + jn)*128 + cbn*16 + wccB)*32 + wo4B];
        }
        __syncthreads();
        const float* sb = pool + cur*2048;
        const float4* wS4 = (const float4*)(pool + 4096 + cur*4096);
        const float4* wG4 = wS4 + 512;
        for (int ccx = 0; ccx < 16; ++ccx) {
            float4 nv = *(const float4*)(sb + ccx*128 + t4);
            #pragma unroll
            for (int i4 = 0; i4 < 2; ++i4) {
                float4 wsv = wS4[ccx*32 + og*2 + i4];
                float4 wgv = wG4[ccx*32 + og*2 + i4];
                int ib = i4*4;
#define ST1(CMP, OO) \
                sA[OO] += nv.x*wsv.CMP; sB[OO] += nv.y*wsv.CMP; sC[OO] += nv.z*wsv.CMP; sD[OO] += nv.w*wsv.CMP; \
                gA[OO] += nv.x*wgv.CMP; gB[OO] += nv.y*wgv.CMP; gC[OO] += nv.z*wgv.CMP; gD[OO] += nv.w*wgv.CMP;
                ST1(x, ib+0) ST1(y, ib+1) ST1(z, ib+2) ST1(w, ib+3)
#undef ST1
            }
        }
    }

    __syncthreads();
    #pragma unroll
    for (int i = 0; i < 8; ++i) {
        float h0 = tanhf(sA[i]) * (1.f/(1.f + __expf(-gA[i])));
        float h1 = tanhf(sB[i]) * (1.f/(1.f + __expf(-gB[i])));
        float h2 = tanhf(sC[i]) * (1.f/(1.f + __expf(-gC[i])));
        float h3 = tanhf(sD[i]) * (1.f/(1.f + __expf(-gD[i])));
        *(float4*)(pool + (o0+i)*128 + t4) = make_float4(h0,h1,h2,h3);
    }

    int aarm = tid >> 8, arest = tid & 255;
    int accx = arest >> 5, ao4 = arest & 31;
    float4 w2r;
    {
        const float4* src = (const float4*)(aarm ? wnTl : woTl);
        w2r = src[(0*8 + accx)*32 + ao4];
    }

    float aA[8], aB[8], aC[8], aD[8], nA[8], nB[8], nC[8], nD[8];
    #pragma unroll
    for (int i = 0; i < 8; ++i) { aA[i]=0.f;aB[i]=0.f;aC[i]=0.f;aD[i]=0.f;nA[i]=0.f;nB[i]=0.f;nC[i]=0.f;nD[i]=0.f; }

    #pragma unroll 1
    for (int cb2 = 0; cb2 < 16; ++cb2) {
        int cur = cb2 & 1;
        ((float4*)(pool + 16384 + cur*2048))[tid] = w2r;
        if (cb2 < 15) {
            const float4* src = (const float4*)(aarm ? wnTl : woTl);
            w2r = src[((cb2+1)*8 + accx)*32 + ao4];
        }
        __syncthreads();
        const float4* w2S = (const float4*)(pool + 16384 + cur*2048);
        const float4* w2N = w2S + 256;
        for (int ccx = 0; ccx < 8; ++ccx) {
            float4 hv = *(const float4*)(pool + (cb2*8 + ccx)*128 + t4);
            #pragma unroll
            for (int i4 = 0; i4 < 2; ++i4) {
                float4 wov = w2S[ccx*32 + og*2 + i4];
                float4 wnv = w2N[ccx*32 + og*2 + i4];
                int ib = i4*4;
#define ST2(CMP, OO) \
                aA[OO] += hv.x*wov.CMP; aB[OO] += hv.y*wov.CMP; aC[OO] += hv.z*wov.CMP; aD[OO] += hv.w*wov.CMP; \
                nA[OO] += hv.x*wnv.CMP; nB[OO] += hv.y*wnv.CMP; nC[OO] += hv.z*wnv.CMP; nD[OO] += hv.w*wnv.CMP;
                ST2(x, ib+0) ST2(y, ib+1) ST2(z, ib+2) ST2(w, ib+3)
#undef ST2
            }
        }
    }

    #pragma unroll
    for (int i = 0; i < 8; ++i) {
        int o = o0 + i;
        float bov = bo[o], bnv = bn[o];
        size_t gi = (size_t)(b*128 + o)*NS + t0 + t4;
        float4 av = first ? make_float4(0.f,0.f,0.f,0.f) : *(const float4*)(acc + gi);
        float4 nf = *(const float4*)(nin + gi);
        *(float4*)(acc + gi)  = make_float4(av.x + aA[i] + bov, av.y + aB[i] + bov,
                                            av.z + aC[i] + bov, av.w + aD[i] + bov);
        *(float4*)(nout + gi) = make_float4(nA[i] + bnv + nf.x, nB[i] + bnv + nf.y,
                                            nC[i] + bnv + nf.z, nD[i] + bnv + nf.w);
    }
}

// ---------------- norms^2 over channels ----------------
__global__ void k_norms(const float* __restrict__ xf, float* __restrict__ norms)
{
    int b = blockIdx.y;
    int t = blockIdx.x*256 + threadIdx.x;
    float a = 0.f;
    for (int c = 0; c < 128; ++c) {
        float v = xf[(size_t)(b*128 + c)*NS + t];
        a += v*v;
    }
    norms[b*NS + t] = a;
}

// ---------------- top-32 per batch (destroys norms) ----------------
__global__ __launch_bounds__(1024) void k_topk(float* __restrict__ norms, float* __restrict__ topv, int* __restrict__ topi)
{
    int b = blockIdx.x;
    int tid = threadIdx.x;
    __shared__ float rv[1024];
    __shared__ int   ri[1024];
    for (int it = 0; it < 32; ++it) {
        float best = -2.f; int bi = 0;
        for (int k = tid; k < NS; k += 1024) {
            float v = norms[b*NS + k];
            if (v > best) { best = v; bi = k; }
        }
        rv[tid] = best; ri[tid] = bi;
        __syncthreads();
        for (int off = 512; off > 0; off >>= 1) {
            if (tid < off) {
                float ov = rv[tid+off]; int oi = ri[tid+off];
                if (ov > rv[tid] || (ov == rv[tid] && oi < ri[tid])) { rv[tid] = ov; ri[tid] = oi; }
            }
            __syncthreads();
        }
        if (tid == 0) {
            topv[b*32 + it] = sqrtf(rv[0]);
            topi[b*32 + it] = ri[0];
            norms[b*NS + ri[0]] = -1.f;
        }
        __syncthreads();
    }
}

// ---------------- gather latents ----------------
__global__ void k_latents(const float* __restrict__ xf, const int* __restrict__ topi, float* __restrict__ lat)
{
    int ev = blockIdx.x; int c = threadIdx.x;
    int b = ev >> 5;
    int idx = topi[ev];
    lat[ev*128 + c] = xf[(size_t)(b*128 + c)*NS + idx];
}

// ---------------- agg = max over time ----------------
__global__ void k_aggmax(const float* __restrict__ xf, float* __restrict__ agg)
{
    int rc = blockIdx.x;
    int tid = threadIdx.x;
    __shared__ float red[256];
    float m = -3.4e38f;
    const float* row = xf + (size_t)rc*NS;
    for (int t = tid; t < NS; t += 256) m = fmaxf(m, row[t]);
    red[tid] = m; __syncthreads();
    for (int off = 128; off > 0; off >>= 1) {
        if (tid < off) red[tid] = fmaxf(red[tid], red[tid+off]);
        __syncthreads();
    }
    if (tid == 0) agg[rc] = red[0];
}

// ---------------- upsample layer for 512 threads ----------------
template<int L2, int NPASS>
__device__ __forceinline__ void up_layerS(const float* __restrict__ wbase, const float* __restrict__ bias,
                                          const float* __restrict__ inb, float* __restrict__ outb,
                                          float* __restrict__ wst, int tid)
{
    constexpr int Lin = L2/2;
    constexpr int OGC = 512/L2;
    constexpr int OR  = 128/NPASS;
    constexpr int NO  = OR/OGC;
    constexpr int LOG = (L2==16)?4:(L2==32)?5:(L2==64)?6:7;
    int p  = tid & (L2-1);
    int og = tid >> LOG;
    int o0 = og*NO;
    #pragma unroll 1
    for (int pass = 0; pass < NPASS; ++pass) {
        int obase = pass*OR;
        float acc[NO];
        #pragma unroll
        for (int k = 0; k < NO; ++k) acc[k] = 0.f;
        #pragma unroll 1
        for (int cc0 = 0; cc0 < 128; cc0 += 16) {
            __syncthreads();
            for (int k = tid; k < 16*3*OR; k += 512) {
                int ci = k / (3*OR); int rem = k - ci*(3*OR);
                int j = rem / OR; int oo = rem - j*OR;
                wst[k] = wbase[(cc0+ci)*384 + j*128 + obase + oo];
            }
            __syncthreads();
            #pragma unroll 1
            for (int ci = 0; ci < 16; ++ci) {
                int c = cc0 + ci;
                float xv[3];
                #pragma unroll
                for (int j = 0; j < 3; ++j) {
                    int iu = p + j - 1;
                    xv[j] = ((unsigned)iu < (unsigned)L2) ? inb[c*Lin + (iu>>1)] : 0.f;
                }
                #pragma unroll
                for (int j = 0; j < 3; ++j) {
                    const float4* w4 = (const float4*)(wst + ci*3*OR + j*OR + o0);
                    #pragma unroll
                    for (int q = 0; q < NO/4; ++q) {
                        float4 w = w4[q];
                        acc[q*4+0] += xv[j]*w.x; acc[q*4+1] += xv[j]*w.y;
                        acc[q*4+2] += xv[j]*w.z; acc[q*4+3] += xv[j]*w.w;
                    }
                }
            }
        }
        #pragma unroll
        for (int k = 0; k < NO; ++k)
            outb[(obase + o0 + k)*L2 + p] = leakyf(acc[k] + bias[obase + o0 + k]);
    }
}

// ---------------- fused conv_up: gridDim=(128 events, 2 modes), 512 threads ----------------
// tf-final: staged LDS weights (r16 structure) + 4p x 2ct thread remap:
// per ci = 1 b128 + 2 b32 xv + 3 b64 weights = 6 LDS issues for 24 FMA (r16: 9 issues).
__global__ __launch_bounds__(512) void k_convup3(const float* __restrict__ lat,
    const float* __restrict__ elw, const float* __restrict__ elb, const float* __restrict__ ecb,
    const float* __restrict__ efw, const float* __restrict__ efb,
    const float* __restrict__ tlw, const float* __restrict__ tlb, const float* __restrict__ tcb,
    const float* __restrict__ tfb, const float* __restrict__ wtu, const float* __restrict__ wtf,
    float* __restrict__ envsq, float* __restrict__ tfT)
{
    __shared__ float pool[35008]; // 136.75 KB
    float* latv = pool;           // 128
    float* bufA = pool + 128;     // 4160
    float* bufB = pool + 4288;    // 8192
    float* bufC = pool + 12480;   // 16384
    float* wst  = pool + 28864;   // 6144
    int ev = blockIdx.x;
    int m  = blockIdx.y;
    int tid = threadIdx.x;
    const float* lw = m ? tlw : elw;
    const float* lb = m ? tlb : elb;
    const float* cb = m ? tcb : ecb;
    const float* wu = wtu + m*4*49152;
    if (tid < 128) latv[tid] = lat[ev*128 + tid];
    __syncthreads();
    for (int jj = tid; jj < 1024; jj += 512) {
        float a = lb[jj];
        const float4* w4 = (const float4*)(lw + jj*128);
        #pragma unroll 8
        for (int q = 0; q < 32; ++q) {
            float4 w = w4[q];
            a += w.x*latv[q*4] + w.y*latv[q*4+1] + w.z*latv[q*4+2] + w.w*latv[q*4+3];
        }
        bufA[(jj>>3)*8 + (jj&7)] = a;
    }
    up_layerS<16,1>(wu,        cb,     bufA, bufB, wst, tid);
    up_layerS<32,1>(wu+49152,  cb+128, bufB, bufA, wst, tid);
    up_layerS<64,2>(wu+98304,  cb+256, bufA, bufB, wst, tid);
    up_layerS<128,4>(wu+147456,cb+384, bufB, bufC, wst, tid);
    __syncthreads();
    if (m == 0) {
        int p = tid & 127, g = tid >> 7;
        float s = 0.f;
        #pragma unroll 1
        for (int c = g*32; c < g*32+32; ++c) {
            #pragma unroll
            for (int j = 0; j < 3; ++j) {
                int iu = p + j - 1;
                float xv = ((unsigned)iu < 128u) ? bufC[c*128 + iu] : 0.f;
                s += efw[c*3+j]*xv;
            }
        }
        wst[g*128 + p] = s;
        __syncthreads();
        if (g == 0) {
            float a = wst[p] + wst[128+p] + wst[256+p] + wst[384+p] + efb[0];
            envsq[ev*128 + p] = a*a;
        }
    } else {
        float* trb = bufA;   // [32ct][stride 132] = 4224 floats (bufA+bufB head, both dead)
        int pl = tid & 31, gg = tid >> 5;   // 16 ct-groups of 2; p = 4*pl..4*pl+3
        int p4 = pl * 4;
        #pragma unroll 1
        for (int ctb = 0; ctb < 17; ++ctb) {
            int ct0 = ctb*32;
            float acc[8];   // [2ct][4p]
            #pragma unroll
            for (int i = 0; i < 8; ++i) acc[i] = 0.f;
            #pragma unroll 1
            for (int cc0 = 0; cc0 < 128; cc0 += 16) {
                __syncthreads();
                for (int k = tid; k < 1536; k += 512) {
                    int ci = k / 96, rem = k - ci*96;
                    int j = rem >> 5, ctl = rem & 31;
                    wst[k] = wtf[(cc0+ci)*1632 + j*544 + ct0 + ctl];
                }
                __syncthreads();
                #pragma unroll 1
                for (int ci = 0; ci < 16; ++ci) {
                    const float* bc = bufC + (cc0 + ci)*128;
                    float4 xc = *(const float4*)(bc + p4);
                    float xm = (pl > 0)  ? bc[p4-1] : 0.f;
                    float xp = (pl < 31) ? bc[p4+4] : 0.f;
                    #pragma unroll
                    for (int j = 0; j < 3; ++j) {
                        float2 w = *(const float2*)(wst + ci*96 + j*32 + gg*2);
                        float v0, v1, v2, v3;
                        if (j == 0)      { v0 = xm;   v1 = xc.x; v2 = xc.y; v3 = xc.z; }
                        else if (j == 1) { v0 = xc.x; v1 = xc.y; v2 = xc.z; v3 = xc.w; }
                        else             { v0 = xc.y; v1 = xc.z; v2 = xc.w; v3 = xp;   }
                        acc[0] += v0*w.x; acc[1] += v1*w.x; acc[2] += v2*w.x; acc[3] += v3*w.x;
                        acc[4] += v0*w.y; acc[5] += v1*w.y; acc[6] += v2*w.y; acc[7] += v3*w.y;
                    }
                }
            }
            __syncthreads();      // prior trb readers done
            *(float4*)(trb + (gg*2+0)*132 + p4) = make_float4(acc[0],acc[1],acc[2],acc[3]);
            *(float4*)(trb + (gg*2+1)*132 + p4) = make_float4(acc[4],acc[5],acc[6],acc[7]);
            __syncthreads();
            int ctl2 = tid & 31, pg = tid >> 5;
            #pragma unroll 1
            for (int ps = 0; ps < 8; ++ps) {
                int pp = ps*16 + pg;
                int ct = ct0 + ctl2;
                if (ct < 514)
                    tfT[(size_t)(ev*128 + pp)*514 + ct] = trb[ctl2*132 + pp] + tfb[ct];
            }
            __syncthreads();
        }
    }
}

// ---------------- impulse transfer lin_stack ----------------
__global__ __launch_bounds__(128) void k_itf(const float* __restrict__ lat,
    const float* __restrict__ iw, const float* __restrict__ ib,
    const float* __restrict__ iow, const float* __restrict__ iob,
    float* __restrict__ itf)
{
    int ev = blockIdx.x; int tid = threadIdx.x;
    __shared__ float xa[128], xb[128];
    xa[tid] = lat[ev*128 + tid];
    __syncthreads();
    float* src = xa; float* dst = xb;
    for (int l = 0; l < 3; ++l) {
        float a = ib[l*128 + tid];
        const float* wr = iw + (l*128 + tid)*128;
        for (int k = 0; k < 128; ++k) a += wr[k]*src[k];
        dst[tid] = leakyf(a);
        __syncthreads();
        float* tmp = src; src = dst; dst = tmp;
    }
    for (int o = tid; o < 514; o += 128) {
        float a = iob[o];
        const float* wr = iow + o*128;
        for (int k = 0; k < 128; ++k) a += wr[k]*src[k];
        itf[ev*514 + o] = a;
    }
}

// ---------------- room/mix lin_stacks + softmax ----------------
__global__ __launch_bounds__(128) void k_roommix(const float* __restrict__ agg,
    const float* __restrict__ rw, const float* __restrict__ rb,
    const float* __restrict__ row_, const float* __restrict__ rob,
    const float* __restrict__ mw, const float* __restrict__ mb,
    const float* __restrict__ mow, const float* __restrict__ mob,
    float* __restrict__ probs, float* __restrict__ mval)
{
    int b = blockIdx.x; int tid = threadIdx.x;
    __shared__ float xa[128], xb[128], rr[8];
    xa[tid] = agg[b*128 + tid];
    __syncthreads();
    float* src = xa; float* dst = xb;
    for (int l = 0; l < 3; ++l) {
        float a = rb[l*128 + tid];
        const float* wr = rw + (l*128 + tid)*128;
        for (int k = 0; k < 128; ++k) a += wr[k]*src[k];
        dst[tid] = leakyf(a);
        __syncthreads();
        float* tmp = src; src = dst; dst = tmp;
    }
    if (tid < 8) {
        float a = rob[tid];
        const float* wr = row_ + tid*128;
        for (int k = 0; k < 128; ++k) a += wr[k]*src[k];
        rr[tid] = a;
    }
    __syncthreads();
    if (tid == 0) {
        float m = rr[0];
        for (int j = 1; j < 8; ++j) m = fmaxf(m, rr[j]);
        float ssum = 0.f; float e[8];
        for (int j = 0; j < 8; ++j) { e[j] = __expf(rr[j]-m); ssum += e[j]; }
        for (int j = 0; j < 8; ++j) probs[b*8+j] = e[j]/ssum;
    }
    __syncthreads();
    xa[tid] = agg[b*128 + tid];
    __syncthreads();
    src = xa; dst = xb;
    for (int l = 0; l < 3; ++l) {
        float a = mb[l*128 + tid];
        const float* wr = mw + (l*128 + tid)*128;
        for (int k = 0; k < 128; ++k) a += wr[k]*src[k];
        dst[tid] = leakyf(a);
        __syncthreads();
        float* tmp = src; src = dst; dst = tmp;
    }
    if (tid == 0) {
        float a = mob[0];
        for (int k = 0; k < 128; ++k) a += mow[k]*src[k];
        mval[b] = a;
    }
}

// ---------------- ir = softmax(r) @ rooms ----------------
__global__ void k_ir(const float* __restrict__ probs, const float* __restrict__ rooms, float* __restrict__ ir)
{
    int b = blockIdx.y;
    int t = blockIdx.x*256 + threadIdx.x;
    float a = 0.f;
    for (int j = 0; j < 8; ++j) a += probs[b*8+j]*rooms[j*NS + t];
    ir[b*NS + t] = a;
}

// ---------------- prep: full Hermitian spectra in bit-reversed order ----------------
__global__ void k_tfprep(const float* __restrict__ tfT, float2* __restrict__ Tscr)
{
    int f = blockIdx.x, ev = blockIdx.y;
    const float* tp = tfT + ((size_t)(ev*128 + f))*514;
    float2* dst = Tscr + ((size_t)(ev*128 + f))*512;
    int t = threadIdx.x;
    #pragma unroll
    for (int h = 0; h < 2; ++h) {
        int slot = t + h*256;
        int pos = (int)(__brev((unsigned)slot) >> 23);
        float2 H;
        if (pos == 0)        H = make_float2(tp[0], 0.f);
        else if (pos == 256) H = make_float2(tp[512], 0.f);
        else if (pos < 256)  H = make_float2(tp[2*pos], tp[2*pos+1]);
        else { int q = 512 - pos; H = make_float2(tp[2*q], -tp[2*q+1]); }
        dst[slot] = H;
    }
}

__global__ void k_itfprep(const float* __restrict__ itf, float2* __restrict__ iscr)
{
    int ev = blockIdx.x;
    const float* tp = itf + (size_t)ev*514;
    float2* dst = iscr + (size_t)ev*512;
    int t = threadIdx.x;
    #pragma unroll
    for (int h = 0; h < 2; ++h) {
        int slot = t + h*256;
        int pos = (int)(__brev((unsigned)slot) >> 23);
        float2 H;
        if (pos == 0)        H = make_float2(tp[0], 0.f);
        else if (pos == 256) H = make_float2(tp[512], 0.f);
        else if (pos < 256)  H = make_float2(tp[2*pos], tp[2*pos+1]);
        else { int q = 512 - pos; H = make_float2(tp[2*q], -tp[2*q+1]); }
        dst[slot] = H;
    }
}

// ---------------- 512-pt real-in filter: DIF fwd (no reorder) * Tscr -> DIT inv ----------------
__device__ __forceinline__ void fft_filt(float nx0, float nx1,
    const float2* __restrict__ Tf,
    float* __restrict__ re, float* __restrict__ im,
    const float* __restrict__ twr, const float* __restrict__ twi,
    int t, float& out0, float& out1)
{
    int w = t >> 6, l = t & 63;
    int c0 = (w << 7) + l;
    {
        float d = nx0 - nx1;
        re[t] = nx0 + nx1; im[t] = 0.f;
        re[t+256] = d * twr[t]; im[t+256] = d * twi[t];
    }
    __syncthreads();
    {
        int i = (t & 127) + ((t >> 7) << 8);
        int j = i & 127;
        float wr = twr[j*2], wi = twi[j*2];
        float ur = re[i], ui = im[i], vr = re[i+128], vi = im[i+128];
        re[i] = ur + vr; im[i] = ui + vi;
        float dr = ur - vr, di = ui - vi;
        re[i+128] = dr*wr - di*wi; im[i+128] = dr*wi + di*wr;
    }
    __syncthreads();
    float a0r = re[c0], a0i = im[c0], a1r = re[c0+64], a1i = im[c0+64];
    {
        float wr = twr[l*4], wi = twi[l*4];
        float ur = a0r, ui = a0i;
        a0r = ur + a1r; a0i = ui + a1i;
        float dr = ur - a1r, di = ui - a1i;
        a1r = dr*wr - di*wi; a1i = dr*wi + di*wr;
    }
#define DIFS(S, TS) { \
        int j = l & (S-1); float wr = twr[j*TS], wi = twi[j*TS]; \
        int up = l & S; \
        float o0r = __shfl_xor(a0r, S, 64), o0i = __shfl_xor(a0i, S, 64); \
        float o1r = __shfl_xor(a1r, S, 64), o1i = __shfl_xor(a1i, S, 64); \
        if (up) { float dr = o0r - a0r, di = o0i - a0i; a0r = dr*wr - di*wi; a0i = dr*wi + di*wr; \
                  float er = o1r - a1r, ei = o1i - a1i; a1r = er*wr - ei*wi; a1i = er*wi + ei*wr; } \
        else    { a0r += o0r; a0i += o0i; a1r += o1r; a1i += o1i; } }
    DIFS(32, 8) DIFS(16, 16) DIFS(8, 32) DIFS(4, 64) DIFS(2, 128) DIFS(1, 256)
#undef DIFS
    {
        float2 T0 = Tf[c0];
        float2 T1 = Tf[c0+64];
        float r = a0r*T0.x - a0i*T0.y; a0i = a0r*T0.y + a0i*T0.x; a0r = r;
        r = a1r*T1.x - a1i*T1.y; a1i = a1r*T1.y + a1i*T1.x; a1r = r;
    }
#define DITS(S, TS) { \
        int j = l & (S-1); float wr = twr[j*TS], wi = -twi[j*TS]; \
        int up = l & S; \
        if (up) { float r = a0r*wr - a0i*wi; a0i = a0r*wi + a0i*wr; a0r = r; \
                  r = a1r*wr - a1i*wi; a1i = a1r*wi + a1i*wr; a1r = r; } \
        float o0r = __shfl_xor(a0r, S, 64), o0i = __shfl_xor(a0i, S, 64); \
        float o1r = __shfl_xor(a1r, S, 64), o1i = __shfl_xor(a1i, S, 64); \
        if (up) { a0r = o0r - a0r; a0i = o0i - a0i; a1r = o1r - a1r; a1i = o1i - a1i; } \
        else    { a0r += o0r; a0i += o0i; a1r += o1r; a1i += o1i; } }
    DITS(1, 256) DITS(2, 128) DITS(4, 64) DITS(8, 32) DITS(16, 16) DITS(32, 8)
#undef DITS
    {
        float wr = twr[l*4], wi = -twi[l*4];
        float vr = a1r*wr - a1i*wi, vi = a1r*wi + a1i*wr;
        a1r = a0r - vr; a1i = a0i - vi;
        a0r += vr; a0i += vi;
    }
    __syncthreads();
    re[c0] = a0r; im[c0] = a0i; re[c0+64] = a1r; im[c0+64] = a1i;
    __syncthreads();
    {
        int i = (t & 127) + ((t >> 7) << 8);
        int j = i & 127;
        float wr = twr[j*2], wi = -twi[j*2];
        float ur = re[i], ui = im[i];
        float br = re[i+128], bi = im[i+128];
        float vr = br*wr - bi*wi, vi = br*wi + bi*wr;
        re[i] = ur + vr; im[i] = ui + vi;
        re[i+128] = ur - vr; im[i+128] = ui - vi;
    }
    __syncthreads();
    {
        float wr = twr[t], wi = -twi[t];
        float ur = re[t];
        float br = re[t+256], bi = im[t+256];
        float vr = br*wr - bi*wi;
        out0 = ur + vr;
        out1 = ur - vr;
    }
}

// ---------------- per-event scan with shuffle-FFT (5 barriers/frame) ----------------
__global__ __launch_bounds__(256) void k_event(const float2* __restrict__ Tscr, const float2* __restrict__ itfscr,
    const float* __restrict__ envsq, const float* __restrict__ noise, float* __restrict__ atoms)
{
    int ev = blockIdx.x; int t = threadIdx.x;
    __shared__ float twr[256], twi[256], re[512], im[512], envl[128];
    if (t < 128) envl[t] = envsq[ev*128 + t];
    {
        float ang = -6.283185307179586f * (float)t / 512.0f;
        float si, co;
        sincosf(ang, &si, &co);
        twr[t] = co; twi[t] = si;
    }
    float ham0 = 0.54f - 0.46f*cosf(6.283185307179586f*(float)t/512.0f);
    float ham1 = 0.54f - 0.46f*cosf(6.283185307179586f*(float)(t+256)/512.0f);
    __syncthreads();
    float imp0, imp1;
    fft_filt(noise[t], noise[t+256], itfscr + (size_t)ev*512, re, im, twr, twi, t, imp0, imp1);
    const float inv512 = 1.f/512.f;
    imp0 *= inv512; imp1 *= inv512;
    float carry0 = 0.f, carry1 = 0.f, accv = 0.f;
    #pragma unroll 1
    for (int f = 0; f < 128; ++f) {
        float e0, e1;
        {
            int tg = f*256 + t;
            float srcp = ((float)tg + 0.5f)*(1.0f/256.0f) - 0.5f;
            srcp = fminf(fmaxf(srcp, 0.f), 127.f);
            int i0 = (int)srcp; float fr = srcp - (float)i0;
            int i1 = i0 + 1; if (i1 > 127) i1 = 127;
            e0 = envl[i0]*(1.f-fr) + envl[i1]*fr;
        }
        {
            int tg = f*256 + 256 + t;
            e1 = 0.f;
            if (tg < NS) {
                float srcp = ((float)tg + 0.5f)*(1.0f/256.0f) - 0.5f;
                srcp = fminf(fmaxf(srcp, 0.f), 127.f);
                int i0 = (int)srcp; float fr = srcp - (float)i0;
                int i1 = i0 + 1; if (i1 > 127) i1 = 127;
                e1 = envl[i0]*(1.f-fr) + envl[i1]*fr;
            }
        }
        float nx0 = imp0*e0 + carry0;
        float nx1 = imp1*e1 + carry1;
        float o0, o1;
        fft_filt(nx0, nx1, Tscr + ((size_t)(ev*128 + f))*512, re, im, twr, twi, t, o0, o1);
        o0 *= inv512 * ham0;
        o1 *= inv512 * ham1;
        atoms[(size_t)ev*NS + f*256 + t] = o0 + accv;
        accv = o1; carry0 = o0; carry1 = o1;
    }
}

// ---------------- final = sum_a values[a]*atoms[a, t-idx[a]] ----------------
__global__ void k_gather(const float* __restrict__ atoms, const float* __restrict__ topv,
                         const int* __restrict__ topi, float* __restrict__ fin)
{
    int b = blockIdx.y;
    int t = blockIdx.x*256 + threadIdx.x;
    float s = 0.f;
    for (int a = 0; a < 32; ++a) {
        int ii = topi[b*32 + a];
        if (ii <= t) s += topv[b*32 + a] * atoms[(size_t)(b*32 + a)*NS + (t - ii)];
    }
    fin[b*NS + t] = s;
}

// ---------------- wet partials ----------------
__global__ __launch_bounds__(256) void k_wetpart(const float* __restrict__ fin, const float* __restrict__ ir,
                                                 float* __restrict__ wetp)
{
    int t0 = blockIdx.x*256;
    int by = blockIdx.y;
    int b = by >> 3, cg = by & 7;
    int tid = threadIdx.x;
    __shared__ float fs[256];
    __shared__ float irw[512];
    float wet = 0.f;
    int nch = t0/256 + 1;
    #pragma unroll 1
    for (int q = cg; q < nch; q += 8) {
        int c0 = q*256;
        __syncthreads();
        fs[tid] = fin[b*NS + c0 + tid];
        int dmin = t0 - c0 - 255;
        for (int qq = tid; qq < 511; qq += 256) {
            int dd = dmin + qq;
            irw[qq] = ((unsigned)dd < NS) ? ir[b*NS + dd] : 0.f;
        }
        __syncthreads();
        if (c0 < t0) {
            #pragma unroll 8
            for (int k = 0; k < 256; ++k) wet += fs[k]*irw[tid + 255 - k];
        } else {
            for (int k = 0; k <= tid; ++k) wet += fs[k]*irw[tid + 255 - k];
        }
    }
    wetp[(size_t)by*NS + t0 + tid] = wet;
}

// ---------------- out = m*sum(wet parts) + fin*(1-m) ----------------
__global__ __launch_bounds__(256) void k_wetsum(const float* __restrict__ fin, const float* __restrict__ wetp,
                                                const float* __restrict__ mval, float* __restrict__ out)
{
    int b = blockIdx.y;
    int t = blockIdx.x*256 + threadIdx.x;
    float w = 0.f;
    #pragma unroll
    for (int cg = 0; cg < 8; ++cg) w += wetp[(size_t)(b*8+cg)*NS + t];
    float m = mval[b];
    float fv = fin[b*NS + t];
    out[b*NS + t] = m*w + fv*(1.f - m);
}

extern "C" void kernel_launch(void* const* d_in, const int* in_sizes, int n_in,
                              void* d_out, int out_size, void* d_ws, size_t ws_size,
                              hipStream_t stream)
{
    (void)in_sizes; (void)n_in; (void)out_size; (void)ws_size;
    const float* x    = (const float*)d_in[0];
    const float* fbw  = (const float*)d_in[1];
    const float* dsw  = (const float*)d_in[2];
    const float* dsb  = (const float*)d_in[3];
    const float* dgw  = (const float*)d_in[4];
    const float* dgb  = (const float*)d_in[5];
    const float* dow  = (const float*)d_in[6];
    const float* dob  = (const float*)d_in[7];
    const float* dnw  = (const float*)d_in[8];
    const float* dnb  = (const float*)d_in[9];
    const float* elw  = (const float*)d_in[10];
    const float* elb  = (const float*)d_in[11];
    const float* ecw  = (const float*)d_in[12];
    const float* ecb  = (const float*)d_in[13];
    const float* efw  = (const float*)d_in[14];
    const float* efb  = (const float*)d_in[15];
    const float* tlw  = (const float*)d_in[16];
    const float* tlb  = (const float*)d_in[17];
    const float* tcw  = (const float*)d_in[18];
    const float* tcb  = (const float*)d_in[19];
    const float* tfw  = (const float*)d_in[20];
    const float* tfb  = (const float*)d_in[21];
    const float* iw   = (const float*)d_in[22];
    const float* ib   = (const float*)d_in[23];
    const float* iow  = (const float*)d_in[24];
    const float* iob  = (const float*)d_in[25];
    const float* rw   = (const float*)d_in[26];
    const float* rb   = (const float*)d_in[27];
    const float* row_ = (const float*)d_in[28];
    const float* rob  = (const float*)d_in[29];
    const float* mw   = (const float*)d_in[30];
    const float* mb   = (const float*)d_in[31];
    const float* mow  = (const float*)d_in[32];
    const float* mob  = (const float*)d_in[33];
    const float* rooms= (const float*)d_in[34];
    const float* noise= (const float*)d_in[35];

    float* ws   = (float*)d_ws;
    float* n0   = ws;                       // 16,777,216
    float* n1   = ws + 16777216;            // 16,777,216
    float* accb = ws + 33554432;            // 16,777,216
    float* wT   = ws + 50331648;            // 1,376,256
    float* woT  = ws + 51707904;            // 114,688
    float* wnT  = ws + 51822592;            // 114,688
    float* envsq= ws + 51937280;            // 16,384
    float* lat  = ws + 51953664;            // 16,384
    float* itfb = ws + 51970048;            // 65,792
    float* norms= ws + 52035840;            // 131,072
    float* topv = ws + 52166912;            // 128
    int*   topi = (int*)(ws + 52167040);    // 128
    float* agg  = ws + 52167168;            // 512
    float* probs= ws + 52167680;            // 32
    float* mval = ws + 52167712;            // 32
    float* irb  = ws + 52167744;            // 131,072
    float* fin  = ws + 52298816;            // 131,072
    float* tfT  = n0;                        // reuse after dilated stack is done
    float* atoms= n0 + 8421376;              // reuse
    float* wetp = n0 + 12615680;             // 1,048,576
    float* wtu  = n1;                        // 393,216  (dead after convup3)
    float* wtf  = n1 + 393216;               // 208,896  (dead after convup3)
    float2* Tscr   = (float2*)n1;            // 128*128*512 float2 (overwrites n1 after convup3)
    float2* itfscr = (float2*)accb;          // (accb dead after aggmax/latents)

    float* out = (float*)d_out;

    k_wtrans<<<dim3((1376256+255)/256), dim3(256), 0, stream>>>(dsw, dgw, wT);
    k_wtrans2<<<dim3((114688+255)/256), dim3(256), 0, stream>>>(dow, dnw, woT, wnT);
    k_front<<<dim3(512,4), dim3(512), 0, stream>>>(x, fbw, n0);

    const int dil[7] = {1,3,9,27,81,243,1};
    float* cin = n0; float* cout = n1;
    for (int l = 0; l < 7; ++l) {
        k_layer<<<dim3(256,4), dim3(512), 0, stream>>>(
            cin, cout, accb, wT + l*98304,
            dsb + l*128, dgb + l*128,
            woT + l*16384, dob + l*128,
            wnT + l*16384, dnb + l*128,
            dil[l], l==0 ? 1 : 0);
        float* tmp = cin; cin = cout; cout = tmp;
    }
    k_norms<<<dim3(128,4), dim3(256), 0, stream>>>(accb, norms);
    k_topk<<<dim3(4), dim3(1024), 0, stream>>>(norms, topv, topi);
    k_latents<<<dim3(128), dim3(128), 0, stream>>>(accb, topi, lat);
    k_aggmax<<<dim3(512), dim3(256), 0, stream>>>(accb, agg);
    k_wtrans_up<<<dim3(1536), dim3(256), 0, stream>>>(ecw, tcw, tfw, wtu, wtf);
    k_convup3<<<dim3(128,2), dim3(512), 0, stream>>>(lat, elw, elb, ecb, efw, efb,
                                                     tlw, tlb, tcb, tfb, wtu, wtf, envsq, tfT);
    k_itf<<<dim3(128), dim3(128), 0, stream>>>(lat, iw, ib, iow, iob, itfb);
    k_roommix<<<dim3(4), dim3(128), 0, stream>>>(agg, rw, rb, row_, rob, mw, mb, mow, mob, probs, mval);
    k_ir<<<dim3(128,4), dim3(256), 0, stream>>>(probs, rooms, irb);
    k_tfprep<<<dim3(128,128), dim3(256), 0, stream>>>(tfT, Tscr);
    k_itfprep<<<dim3(128), dim3(256), 0, stream>>>(itfb, itfscr);
    k_event<<<dim3(128), dim3(256), 0, stream>>>(Tscr, itfscr, envsq, noise, atoms);
    k_gather<<<dim3(128,4), dim3(256), 0, stream>>>(atoms, topv, topi, fin);
    k_wetpart<<<dim3(128,32), dim3(256), 0, stream>>>(fin, irb, wetp);
    k_wetsum<<<dim3(128,4), dim3(256), 0, stream>>>(fin, wetp, mval, out);
}

// Round 19
// 4650.821 us; speedup vs baseline: 1.1416x; 1.0750x over previous
//
#include <hip/hip_runtime.h>
#include <math.h>

#define NS 32768

static __device__ __forceinline__ float leakyf(float x){ return x >= 0.f ? x : 0.2f*x; }

// ---------------- weight transpose for dilated stack: wT[l][sg][j][cc][o] ----------------
__global__ void k_wtrans(const float* __restrict__ ws, const float* __restrict__ wg, float* __restrict__ wT)
{
    int idx = blockIdx.x*256 + threadIdx.x;
    const int total = 7*2*3*128*128;
    if (idx >= total) return;
    int o  = idx & 127;
    int cc = (idx >> 7) & 127;
    int j  = (idx >> 14) % 3;
    int sg = (idx / 49152) & 1;
    int l  = idx / 98304;
    const float* src = sg ? wg : ws;
    wT[idx] = src[((l*128 + o)*128 + cc)*3 + j];
}

// ---------------- stage-2 weight transpose: woT/wnT [l][c][o] ----------------
__global__ void k_wtrans2(const float* __restrict__ wo, const float* __restrict__ wn,
                          float* __restrict__ woT, float* __restrict__ wnT)
{
    int idx = blockIdx.x*256 + threadIdx.x;
    if (idx >= 7*128*128) return;
    int o = idx & 127;
    int c = (idx >> 7) & 127;
    int l = idx >> 14;
    woT[idx] = wo[(l*128 + o)*128 + c];
    wnT[idx] = wn[(l*128 + o)*128 + c];
}

// ---------------- conv_up weight transposes ----------------
__global__ void k_wtrans_up(const float* __restrict__ ecw, const float* __restrict__ tcw,
                            const float* __restrict__ tfw, float* __restrict__ wtu, float* __restrict__ wtf)
{
    int idx = blockIdx.x*256 + threadIdx.x;
    if (idx < 393216) {
        int o = idx & 127;
        int j = (idx >> 7) % 3;
        int c = (idx / 384) & 127;
        int ml = idx / 49152;
        const float* src = (ml < 4 ? ecw : tcw) + (ml & 3)*49152;
        wtu[idx] = src[(o*128 + c)*3 + j];
    }
    if (idx < 208896) {
        int ct = idx % 544;
        int j = (idx / 544) % 3;
        int c = idx / 1632;
        wtf[idx] = (ct < 514) ? tfw[(ct*128 + c)*3 + j] : 0.f;
    }
}

// ---------------- front conv: n[b,c,t] = sum_k x[b, t+k-256] * fbw[c,k] ----------------
__global__ __launch_bounds__(512) void k_front(const float* __restrict__ x, const float* __restrict__ fbw,
                                               float* __restrict__ n0)
{
    int b = blockIdx.y;
    int t0 = blockIdx.x * 64;
    int tid = threadIdx.x;
    int t = tid & 63, og = tid >> 6;
    __shared__ float xs[576];
    __shared__ float4 wl[2048];
    for (int i = tid; i < 575; i += 512) {
        int p = t0 + i - 256;
        xs[i] = ((unsigned)p < NS) ? x[b*NS + p] : 0.f;
    }
    float s[16];
    #pragma unroll
    for (int i = 0; i < 16; ++i) s[i] = 0.f;
    for (int kc = 0; kc < 8; ++kc) {
        __syncthreads();
        for (int i = tid; i < 2048; i += 512) {
            int c = i >> 4, k4 = i & 15;
            wl[i] = *(const float4*)(fbw + c*512 + kc*64 + k4*4);
        }
        __syncthreads();
        for (int k4 = 0; k4 < 16; ++k4) {
            int base = t + kc*64 + k4*4;
            float xv0 = xs[base+0], xv1 = xs[base+1], xv2 = xs[base+2], xv3 = xs[base+3];
            #pragma unroll
            for (int i = 0; i < 16; ++i) {
                float4 w = wl[(og*16 + i)*16 + k4];
                s[i] += w.x*xv0 + w.y*xv1 + w.z*xv2 + w.w*xv3;
            }
        }
    }
    #pragma unroll
    for (int i = 0; i < 16; ++i)
        n0[(size_t)(b*128 + og*16 + i)*NS + t0 + t] = s[i];
}

// ---------------- one dilated gated layer: 4 contiguous t-points/thread, 8 o/thread ----------------
__global__ __launch_bounds__(512) void k_layer(const float* __restrict__ nin, float* __restrict__ nout,
        float* __restrict__ acc, const float* __restrict__ wTl,
        const float* __restrict__ bs, const float* __restrict__ bg,
        const float* __restrict__ woTl, const float* __restrict__ bo,
        const float* __restrict__ wnTl, const float* __restrict__ bn,
        int d, int first)
{
    __shared__ float pool[20480]; // 80 KB
    int b = blockIdx.y;
    int t0 = blockIdx.x * 128;
    int tid = threadIdx.x;
    int l = tid & 31, og = tid >> 5;   // 16 o-groups of 8
    int o0 = og * 8;
    int t4 = l * 4;
    const float* nb = nin + (size_t)b*128*NS;
    const float4* wq = (const float4*)wTl;

    int sci = tid >> 5;
    int st4 = (tid & 31) * 4;
    int wsgA = 0,              wccA = (tid >> 5) & 15,        wo4A = tid & 31;
    int wsgB = (tid+512) >> 9, wccB = ((tid+512) >> 5) & 15,  wo4B = (tid+512) & 31;

    float4 sreg, wr0, wr1;
    {
        int p = t0 + st4 - d;
        const float* bp = nb + (size_t)sci*NS;
        float v0 = ((unsigned)(p+0) < NS) ? bp[p+0] : 0.f;
        float v1 = ((unsigned)(p+1) < NS) ? bp[p+1] : 0.f;
        float v2 = ((unsigned)(p+2) < NS) ? bp[p+2] : 0.f;
        float v3 = ((unsigned)(p+3) < NS) ? bp[p+3] : 0.f;
        sreg = make_float4(v0,v1,v2,v3);
        wr0 = wq[((wsgA*3 + 0)*128 + wccA)*32 + wo4A];
        wr1 = wq[((wsgB*3 + 0)*128 + wccB)*32 + wo4B];
    }

    float sA[8], sB[8], sC[8], sD[8], gA[8], gB[8], gC[8], gD[8];
    #pragma unroll
    for (int i = 0; i < 8; ++i) {
        float bv = bs[o0+i], gv = bg[o0+i];
        sA[i]=bv; sB[i]=bv; sC[i]=bv; sD[i]=bv;
        gA[i]=gv; gB[i]=gv; gC[i]=gv; gD[i]=gv;
    }

    #pragma unroll 1
    for (int cnt = 0; cnt < 24; ++cnt) {
        int cur = cnt & 1;
        ((float4*)(pool + cur*2048))[tid] = sreg;
        {
            float4* wb = (float4*)(pool + 4096 + cur*4096);
            wb[tid] = wr0; wb[tid + 512] = wr1;
        }
        if (cnt < 23) {
            int nxt = cnt + 1;
            int jn = nxt >> 3, cbn = nxt & 7;
            int p = t0 + st4 + (jn-1)*d;
            const float* bp = nb + (size_t)(cbn*16 + sci)*NS;
            float v0 = ((unsigned)(p+0) < NS) ? bp[p+0] : 0.f;
            float v1 = ((unsigned)(p+1) < NS) ? bp[p+1] : 0.f;
            float v2 = ((unsigned)(p+2) < NS) ? bp[p+2] : 0.f;
            float v3 = ((unsigned)(p+3) < NS) ? bp[p+3] : 0.f;
            sreg = make_float4(v0,v1,v2,v3);
            wr0 = wq[((wsgA*3 + jn)*128 + cbn*16 + wccA)*32 + wo4A];
            wr1 = wq[((wsgB*3 + jn)*128 + cbn*16 + wccB)*32 + wo4B];
        }
        __syncthreads();
        const float* sb = pool + cur*2048;
        const float4* wS4 = (const float4*)(pool + 4096 + cur*4096);
        const float4* wG4 = wS4 + 512;
        for (int ccx = 0; ccx < 16; ++ccx) {
            float4 nv = *(const float4*)(sb + ccx*128 + t4);
            #pragma unroll
            for (int i4 = 0; i4 < 2; ++i4) {
                float4 wsv = wS4[ccx*32 + og*2 + i4];
                float4 wgv = wG4[ccx*32 + og*2 + i4];
                int ib = i4*4;
#define ST1(CMP, OO) \
                sA[OO] += nv.x*wsv.CMP; sB[OO] += nv.y*wsv.CMP; sC[OO] += nv.z*wsv.CMP; sD[OO] += nv.w*wsv.CMP; \
                gA[OO] += nv.x*wgv.CMP; gB[OO] += nv.y*wgv.CMP; gC[OO] += nv.z*wgv.CMP; gD[OO] += nv.w*wgv.CMP;
                ST1(x, ib+0) ST1(y, ib+1) ST1(z, ib+2) ST1(w, ib+3)
#undef ST1
            }
        }
    }

    __syncthreads();
    #pragma unroll
    for (int i = 0; i < 8; ++i) {
        float h0 = tanhf(sA[i]) * (1.f/(1.f + __expf(-gA[i])));
        float h1 = tanhf(sB[i]) * (1.f/(1.f + __expf(-gB[i])));
        float h2 = tanhf(sC[i]) * (1.f/(1.f + __expf(-gC[i])));
        float h3 = tanhf(sD[i]) * (1.f/(1.f + __expf(-gD[i])));
        *(float4*)(pool + (o0+i)*128 + t4) = make_float4(h0,h1,h2,h3);
    }

    int aarm = tid >> 8, arest = tid & 255;
    int accx = arest >> 5, ao4 = arest & 31;
    float4 w2r;
    {
        const float4* src = (const float4*)(aarm ? wnTl : woTl);
        w2r = src[(0*8 + accx)*32 + ao4];
    }

    float aA[8], aB[8], aC[8], aD[8], nA[8], nB[8], nC[8], nD[8];
    #pragma unroll
    for (int i = 0; i < 8; ++i) { aA[i]=0.f;aB[i]=0.f;aC[i]=0.f;aD[i]=0.f;nA[i]=0.f;nB[i]=0.f;nC[i]=0.f;nD[i]=0.f; }

    #pragma unroll 1
    for (int cb2 = 0; cb2 < 16; ++cb2) {
        int cur = cb2 & 1;
        ((float4*)(pool + 16384 + cur*2048))[tid] = w2r;
        if (cb2 < 15) {
            const float4* src = (const float4*)(aarm ? wnTl : woTl);
            w2r = src[((cb2+1)*8 + accx)*32 + ao4];
        }
        __syncthreads();
        const float4* w2S = (const float4*)(pool + 16384 + cur*2048);
        const float4* w2N = w2S + 256;
        for (int ccx = 0; ccx < 8; ++ccx) {
            float4 hv = *(const float4*)(pool + (cb2*8 + ccx)*128 + t4);
            #pragma unroll
            for (int i4 = 0; i4 < 2; ++i4) {
                float4 wov = w2S[ccx*32 + og*2 + i4];
                float4 wnv = w2N[ccx*32 + og*2 + i4];
                int ib = i4*4;
#define ST2(CMP, OO) \
                aA[OO] += hv.x*wov.CMP; aB[OO] += hv.y*wov.CMP; aC[OO] += hv.z*wov.CMP; aD[OO] += hv.w*wov.CMP; \
                nA[OO] += hv.x*wnv.CMP; nB[OO] += hv.y*wnv.CMP; nC[OO] += hv.z*wnv.CMP; nD[OO] += hv.w*wnv.CMP;
                ST2(x, ib+0) ST2(y, ib+1) ST2(z, ib+2) ST2(w, ib+3)
#undef ST2
            }
        }
    }

    #pragma unroll
    for (int i = 0; i < 8; ++i) {
        int o = o0 + i;
        float bov = bo[o], bnv = bn[o];
        size_t gi = (size_t)(b*128 + o)*NS + t0 + t4;
        float4 av = first ? make_float4(0.f,0.f,0.f,0.f) : *(const float4*)(acc + gi);
        float4 nf = *(const float4*)(nin + gi);
        *(float4*)(acc + gi)  = make_float4(av.x + aA[i] + bov, av.y + aB[i] + bov,
                                            av.z + aC[i] + bov, av.w + aD[i] + bov);
        *(float4*)(nout + gi) = make_float4(nA[i] + bnv + nf.x, nB[i] + bnv + nf.y,
                                            nC[i] + bnv + nf.z, nD[i] + bnv + nf.w);
    }
}

// ---------------- norms^2 over channels ----------------
__global__ void k_norms(const float* __restrict__ xf, float* __restrict__ norms)
{
    int b = blockIdx.y;
    int t = blockIdx.x*256 + threadIdx.x;
    float a = 0.f;
    for (int c = 0; c < 128; ++c) {
        float v = xf[(size_t)(b*128 + c)*NS + t];
        a += v*v;
    }
    norms[b*NS + t] = a;
}

// ---------------- top-32 per batch (destroys norms) ----------------
__global__ __launch_bounds__(1024) void k_topk(float* __restrict__ norms, float* __restrict__ topv, int* __restrict__ topi)
{
    int b = blockIdx.x;
    int tid = threadIdx.x;
    __shared__ float rv[1024];
    __shared__ int   ri[1024];
    for (int it = 0; it < 32; ++it) {
        float best = -2.f; int bi = 0;
        for (int k = tid; k < NS; k += 1024) {
            float v = norms[b*NS + k];
            if (v > best) { best = v; bi = k; }
        }
        rv[tid] = best; ri[tid] = bi;
        __syncthreads();
        for (int off = 512; off > 0; off >>= 1) {
            if (tid < off) {
                float ov = rv[tid+off]; int oi = ri[tid+off];
                if (ov > rv[tid] || (ov == rv[tid] && oi < ri[tid])) { rv[tid] = ov; ri[tid] = oi; }
            }
            __syncthreads();
        }
        if (tid == 0) {
            topv[b*32 + it] = sqrtf(rv[0]);
            topi[b*32 + it] = ri[0];
            norms[b*NS + ri[0]] = -1.f;
        }
        __syncthreads();
    }
}

// ---------------- gather latents ----------------
__global__ void k_latents(const float* __restrict__ xf, const int* __restrict__ topi, float* __restrict__ lat)
{
    int ev = blockIdx.x; int c = threadIdx.x;
    int b = ev >> 5;
    int idx = topi[ev];
    lat[ev*128 + c] = xf[(size_t)(b*128 + c)*NS + idx];
}

// ---------------- agg = max over time ----------------
__global__ void k_aggmax(const float* __restrict__ xf, float* __restrict__ agg)
{
    int rc = blockIdx.x;
    int tid = threadIdx.x;
    __shared__ float red[256];
    float m = -3.4e38f;
    const float* row = xf + (size_t)rc*NS;
    for (int t = tid; t < NS; t += 256) m = fmaxf(m, row[t]);
    red[tid] = m; __syncthreads();
    for (int off = 128; off > 0; off >>= 1) {
        if (tid < off) red[tid] = fmaxf(red[tid], red[tid+off]);
        __syncthreads();
    }
    if (tid == 0) agg[rc] = red[0];
}

// ---------------- upsample layer for 512 threads ----------------
template<int L2, int NPASS>
__device__ __forceinline__ void up_layerS(const float* __restrict__ wbase, const float* __restrict__ bias,
                                          const float* __restrict__ inb, float* __restrict__ outb,
                                          float* __restrict__ wst, int tid)
{
    constexpr int Lin = L2/2;
    constexpr int OGC = 512/L2;
    constexpr int OR  = 128/NPASS;
    constexpr int NO  = OR/OGC;
    constexpr int LOG = (L2==16)?4:(L2==32)?5:(L2==64)?6:7;
    int p  = tid & (L2-1);
    int og = tid >> LOG;
    int o0 = og*NO;
    #pragma unroll 1
    for (int pass = 0; pass < NPASS; ++pass) {
        int obase = pass*OR;
        float acc[NO];
        #pragma unroll
        for (int k = 0; k < NO; ++k) acc[k] = 0.f;
        #pragma unroll 1
        for (int cc0 = 0; cc0 < 128; cc0 += 16) {
            __syncthreads();
            for (int k = tid; k < 16*3*OR; k += 512) {
                int ci = k / (3*OR); int rem = k - ci*(3*OR);
                int j = rem / OR; int oo = rem - j*OR;
                wst[k] = wbase[(cc0+ci)*384 + j*128 + obase + oo];
            }
            __syncthreads();
            #pragma unroll 1
            for (int ci = 0; ci < 16; ++ci) {
                int c = cc0 + ci;
                float xv[3];
                #pragma unroll
                for (int j = 0; j < 3; ++j) {
                    int iu = p + j - 1;
                    xv[j] = ((unsigned)iu < (unsigned)L2) ? inb[c*Lin + (iu>>1)] : 0.f;
                }
                #pragma unroll
                for (int j = 0; j < 3; ++j) {
                    const float4* w4 = (const float4*)(wst + ci*3*OR + j*OR + o0);
                    #pragma unroll
                    for (int q = 0; q < NO/4; ++q) {
                        float4 w = w4[q];
                        acc[q*4+0] += xv[j]*w.x; acc[q*4+1] += xv[j]*w.y;
                        acc[q*4+2] += xv[j]*w.z; acc[q*4+3] += xv[j]*w.w;
                    }
                }
            }
        }
        #pragma unroll
        for (int k = 0; k < NO; ++k)
            outb[(obase + o0 + k)*L2 + p] = leakyf(acc[k] + bias[obase + o0 + k]);
    }
}

// ---------------- fused conv_up: gridDim=(128 events, 2 modes), 512 threads ----------------
// mode 0: env head; mode 1: writes bufC (X) to global for the separate k_tffin kernel.
__global__ __launch_bounds__(512) void k_convup3(const float* __restrict__ lat,
    const float* __restrict__ elw, const float* __restrict__ elb, const float* __restrict__ ecb,
    const float* __restrict__ efw, const float* __restrict__ efb,
    const float* __restrict__ tlw, const float* __restrict__ tlb, const float* __restrict__ tcb,
    const float* __restrict__ wtu,
    float* __restrict__ envsq, float* __restrict__ Xg)
{
    __shared__ float pool[35008]; // 136.75 KB
    float* latv = pool;           // 128
    float* bufA = pool + 128;     // 4160
    float* bufB = pool + 4288;    // 8192
    float* bufC = pool + 12480;   // 16384
    float* wst  = pool + 28864;   // 6144
    int ev = blockIdx.x;
    int m  = blockIdx.y;
    int tid = threadIdx.x;
    const float* lw = m ? tlw : elw;
    const float* lb = m ? tlb : elb;
    const float* cb = m ? tcb : ecb;
    const float* wu = wtu + m*4*49152;
    if (tid < 128) latv[tid] = lat[ev*128 + tid];
    __syncthreads();
    for (int jj = tid; jj < 1024; jj += 512) {
        float a = lb[jj];
        const float4* w4 = (const float4*)(lw + jj*128);
        #pragma unroll 8
        for (int q = 0; q < 32; ++q) {
            float4 w = w4[q];
            a += w.x*latv[q*4] + w.y*latv[q*4+1] + w.z*latv[q*4+2] + w.w*latv[q*4+3];
        }
        bufA[(jj>>3)*8 + (jj&7)] = a;
    }
    up_layerS<16,1>(wu,        cb,     bufA, bufB, wst, tid);
    up_layerS<32,1>(wu+49152,  cb+128, bufB, bufA, wst, tid);
    up_layerS<64,2>(wu+98304,  cb+256, bufA, bufB, wst, tid);
    up_layerS<128,4>(wu+147456,cb+384, bufB, bufC, wst, tid);
    __syncthreads();
    if (m == 0) {
        int p = tid & 127, g = tid >> 7;
        float s = 0.f;
        #pragma unroll 1
        for (int c = g*32; c < g*32+32; ++c) {
            #pragma unroll
            for (int j = 0; j < 3; ++j) {
                int iu = p + j - 1;
                float xv = ((unsigned)iu < 128u) ? bufC[c*128 + iu] : 0.f;
                s += efw[c*3+j]*xv;
            }
        }
        wst[g*128 + p] = s;
        __syncthreads();
        if (g == 0) {
            float a = wst[p] + wst[128+p] + wst[256+p] + wst[384+p] + efb[0];
            envsq[ev*128 + p] = a*a;
        }
    } else {
        float* xg = Xg + (size_t)ev*16384;
        for (int k = tid*4; k < 16384; k += 2048)
            *(float4*)(xg + k) = *(const float4*)(bufC + k);
    }
}

// ---------------- tf final conv: grid (17 ct-tiles, 128 ev), 256 threads, 70KB LDS ----------------
// X staged once (64KB); weight chunks staged; wave-uniform b128 broadcasts; coalesced
// writes to transposed layout tfTt[ev][ct][p].
__global__ __launch_bounds__(256) void k_tffin(const float* __restrict__ Xg, const float* __restrict__ wtf,
                                               const float* __restrict__ tfb, float* __restrict__ tfTt)
{
    __shared__ float pool[17920]; // 70 KB: X 16384 + wst 1536
    float* Xs  = pool;
    float* wst = pool + 16384;
    int ctb = blockIdx.x, ev = blockIdx.y;
    int ct0 = ctb*32;
    int tid = threadIdx.x;
    int p = tid & 127, g = tid >> 7;   // g in 0..1, 16 ct each
    const float* xg = Xg + (size_t)ev*16384;
    for (int k = tid*4; k < 16384; k += 1024)
        *(float4*)(Xs + k) = *(const float4*)(xg + k);
    float acc[16];
    #pragma unroll
    for (int i = 0; i < 16; ++i) acc[i] = 0.f;
    #pragma unroll 1
    for (int cc0 = 0; cc0 < 128; cc0 += 16) {
        __syncthreads();   // X staged (first) / prior wst reads done
        for (int k = tid; k < 1536; k += 256) {
            int ci = k / 96, rem = k - ci*96;
            int j = rem >> 5, ctl = rem & 31;
            wst[k] = wtf[(cc0+ci)*1632 + j*544 + ct0 + ctl];
        }
        __syncthreads();
        #pragma unroll 1
        for (int ci = 0; ci < 16; ++ci) {
            const float* in = Xs + (cc0 + ci)*128;
            float xm = (p >= 1)  ? in[p-1] : 0.f;
            float x0 = in[p];
            float xp = (p < 127) ? in[p+1] : 0.f;
            #pragma unroll
            for (int j = 0; j < 3; ++j) {
                float xv = (j == 0) ? xm : ((j == 1) ? x0 : xp);
                const float4* w4 = (const float4*)(wst + ci*96 + j*32 + g*16);
                #pragma unroll
                for (int q = 0; q < 4; ++q) {
                    float4 w = w4[q];
                    acc[q*4+0] += xv*w.x; acc[q*4+1] += xv*w.y;
                    acc[q*4+2] += xv*w.z; acc[q*4+3] += xv*w.w;
                }
            }
        }
    }
    #pragma unroll
    for (int i = 0; i < 16; ++i) {
        int ct = ct0 + g*16 + i;
        float bias = (ct < 514) ? tfb[ct] : 0.f;
        tfTt[((size_t)ev*544 + ct)*128 + p] = acc[i] + bias;
    }
}

// ---------------- impulse transfer lin_stack ----------------
__global__ __launch_bounds__(128) void k_itf(const float* __restrict__ lat,
    const float* __restrict__ iw, const float* __restrict__ ib,
    const float* __restrict__ iow, const float* __restrict__ iob,
    float* __restrict__ itf)
{
    int ev = blockIdx.x; int tid = threadIdx.x;
    __shared__ float xa[128], xb[128];
    xa[tid] = lat[ev*128 + tid];
    __syncthreads();
    float* src = xa; float* dst = xb;
    for (int l = 0; l < 3; ++l) {
        float a = ib[l*128 + tid];
        const float* wr = iw + (l*128 + tid)*128;
        for (int k = 0; k < 128; ++k) a += wr[k]*src[k];
        dst[tid] = leakyf(a);
        __syncthreads();
        float* tmp = src; src = dst; dst = tmp;
    }
    for (int o = tid; o < 514; o += 128) {
        float a = iob[o];
        const float* wr = iow + o*128;
        for (int k = 0; k < 128; ++k) a += wr[k]*src[k];
        itf[ev*514 + o] = a;
    }
}

// ---------------- room/mix lin_stacks + softmax ----------------
__global__ __launch_bounds__(128) void k_roommix(const float* __restrict__ agg,
    const float* __restrict__ rw, const float* __restrict__ rb,
    const float* __restrict__ row_, const float* __restrict__ rob,
    const float* __restrict__ mw, const float* __restrict__ mb,
    const float* __restrict__ mow, const float* __restrict__ mob,
    float* __restrict__ probs, float* __restrict__ mval)
{
    int b = blockIdx.x; int tid = threadIdx.x;
    __shared__ float xa[128], xb[128], rr[8];
    xa[tid] = agg[b*128 + tid];
    __syncthreads();
    float* src = xa; float* dst = xb;
    for (int l = 0; l < 3; ++l) {
        float a = rb[l*128 + tid];
        const float* wr = rw + (l*128 + tid)*128;
        for (int k = 0; k < 128; ++k) a += wr[k]*src[k];
        dst[tid] = leakyf(a);
        __syncthreads();
        float* tmp = src; src = dst; dst = tmp;
    }
    if (tid < 8) {
        float a = rob[tid];
        const float* wr = row_ + tid*128;
        for (int k = 0; k < 128; ++k) a += wr[k]*src[k];
        rr[tid] = a;
    }
    __syncthreads();
    if (tid == 0) {
        float m = rr[0];
        for (int j = 1; j < 8; ++j) m = fmaxf(m, rr[j]);
        float ssum = 0.f; float e[8];
        for (int j = 0; j < 8; ++j) { e[j] = __expf(rr[j]-m); ssum += e[j]; }
        for (int j = 0; j < 8; ++j) probs[b*8+j] = e[j]/ssum;
    }
    __syncthreads();
    xa[tid] = agg[b*128 + tid];
    __syncthreads();
    src = xa; dst = xb;
    for (int l = 0; l < 3; ++l) {
        float a = mb[l*128 + tid];
        const float* wr = mw + (l*128 + tid)*128;
        for (int k = 0; k < 128; ++k) a += wr[k]*src[k];
        dst[tid] = leakyf(a);
        __syncthreads();
        float* tmp = src; src = dst; dst = tmp;
    }
    if (tid == 0) {
        float a = mob[0];
        for (int k = 0; k < 128; ++k) a += mow[k]*src[k];
        mval[b] = a;
    }
}

// ---------------- ir = softmax(r) @ rooms ----------------
__global__ void k_ir(const float* __restrict__ probs, const float* __restrict__ rooms, float* __restrict__ ir)
{
    int b = blockIdx.y;
    int t = blockIdx.x*256 + threadIdx.x;
    float a = 0.f;
    for (int j = 0; j < 8; ++j) a += probs[b*8+j]*rooms[j*NS + t];
    ir[b*NS + t] = a;
}

// ---------------- prep: full Hermitian spectra in bit-reversed order (reads tfTt[ev][ct][p]) ----------------
__global__ void k_tfprep(const float* __restrict__ tfTt, float2* __restrict__ Tscr)
{
    int f = blockIdx.x, ev = blockIdx.y;
    const float* tp = tfTt + (size_t)ev*544*128;
    float2* dst = Tscr + ((size_t)(ev*128 + f))*512;
    int t = threadIdx.x;
    #pragma unroll
    for (int h = 0; h < 2; ++h) {
        int slot = t + h*256;
        int pos = (int)(__brev((unsigned)slot) >> 23);
        float2 H;
        if (pos == 0)        H = make_float2(tp[0*128 + f], 0.f);
        else if (pos == 256) H = make_float2(tp[512*128 + f], 0.f);
        else if (pos < 256)  H = make_float2(tp[(2*pos)*128 + f], tp[(2*pos+1)*128 + f]);
        else { int q = 512 - pos; H = make_float2(tp[(2*q)*128 + f], -tp[(2*q+1)*128 + f]); }
        dst[slot] = H;
    }
}

__global__ void k_itfprep(const float* __restrict__ itf, float2* __restrict__ iscr)
{
    int ev = blockIdx.x;
    const float* tp = itf + (size_t)ev*514;
    float2* dst = iscr + (size_t)ev*512;
    int t = threadIdx.x;
    #pragma unroll
    for (int h = 0; h < 2; ++h) {
        int slot = t + h*256;
        int pos = (int)(__brev((unsigned)slot) >> 23);
        float2 H;
        if (pos == 0)        H = make_float2(tp[0], 0.f);
        else if (pos == 256) H = make_float2(tp[512], 0.f);
        else if (pos < 256)  H = make_float2(tp[2*pos], tp[2*pos+1]);
        else { int q = 512 - pos; H = make_float2(tp[2*q], -tp[2*q+1]); }
        dst[slot] = H;
    }
}

// ---------------- 512-pt real-in filter: DIF fwd (no reorder) * Tscr -> DIT inv ----------------
__device__ __forceinline__ void fft_filt(float nx0, float nx1,
    const float2* __restrict__ Tf,
    float* __restrict__ re, float* __restrict__ im,
    const float* __restrict__ twr, const float* __restrict__ twi,
    int t, float& out0, float& out1)
{
    int w = t >> 6, l = t & 63;
    int c0 = (w << 7) + l;
    {
        float d = nx0 - nx1;
        re[t] = nx0 + nx1; im[t] = 0.f;
        re[t+256] = d * twr[t]; im[t+256] = d * twi[t];
    }
    __syncthreads();
    {
        int i = (t & 127) + ((t >> 7) << 8);
        int j = i & 127;
        float wr = twr[j*2], wi = twi[j*2];
        float ur = re[i], ui = im[i], vr = re[i+128], vi = im[i+128];
        re[i] = ur + vr; im[i] = ui + vi;
        float dr = ur - vr, di = ui - vi;
        re[i+128] = dr*wr - di*wi; im[i+128] = dr*wi + di*wr;
    }
    __syncthreads();
    float a0r = re[c0], a0i = im[c0], a1r = re[c0+64], a1i = im[c0+64];
    {
        float wr = twr[l*4], wi = twi[l*4];
        float ur = a0r, ui = a0i;
        a0r = ur + a1r; a0i = ui + a1i;
        float dr = ur - a1r, di = ui - a1i;
        a1r = dr*wr - di*wi; a1i = dr*wi + di*wr;
    }
#define DIFS(S, TS) { \
        int j = l & (S-1); float wr = twr[j*TS], wi = twi[j*TS]; \
        int up = l & S; \
        float o0r = __shfl_xor(a0r, S, 64), o0i = __shfl_xor(a0i, S, 64); \
        float o1r = __shfl_xor(a1r, S, 64), o1i = __shfl_xor(a1i, S, 64); \
        if (up) { float dr = o0r - a0r, di = o0i - a0i; a0r = dr*wr - di*wi; a0i = dr*wi + di*wr; \
                  float er = o1r - a1r, ei = o1i - a1i; a1r = er*wr - ei*wi; a1i = er*wi + ei*wr; } \
        else    { a0r += o0r; a0i += o0i; a1r += o1r; a1i += o1i; } }
    DIFS(32, 8) DIFS(16, 16) DIFS(8, 32) DIFS(4, 64) DIFS(2, 128) DIFS(1, 256)
#undef DIFS
    {
        float2 T0 = Tf[c0];
        float2 T1 = Tf[c0+64];
        float r = a0r*T0.x - a0i*T0.y; a0i = a0r*T0.y + a0i*T0.x; a0r = r;
        r = a1r*T1.x - a1i*T1.y; a1i = a1r*T1.y + a1i*T1.x; a1r = r;
    }
#define DITS(S, TS) { \
        int j = l & (S-1); float wr = twr[j*TS], wi = -twi[j*TS]; \
        int up = l & S; \
        if (up) { float r = a0r*wr - a0i*wi; a0i = a0r*wi + a0i*wr; a0r = r; \
                  r = a1r*wr - a1i*wi; a1i = a1r*wi + a1i*wr; a1r = r; } \
        float o0r = __shfl_xor(a0r, S, 64), o0i = __shfl_xor(a0i, S, 64); \
        float o1r = __shfl_xor(a1r, S, 64), o1i = __shfl_xor(a1i, S, 64); \
        if (up) { a0r = o0r - a0r; a0i = o0i - a0i; a1r = o1r - a1r; a1i = o1i - a1i; } \
        else    { a0r += o0r; a0i += o0i; a1r += o1r; a1i += o1i; } }
    DITS(1, 256) DITS(2, 128) DITS(4, 64) DITS(8, 32) DITS(16, 16) DITS(32, 8)
#undef DITS
    {
        float wr = twr[l*4], wi = -twi[l*4];
        float vr = a1r*wr - a1i*wi, vi = a1r*wi + a1i*wr;
        a1r = a0r - vr; a1i = a0i - vi;
        a0r += vr; a0i += vi;
    }
    __syncthreads();
    re[c0] = a0r; im[c0] = a0i; re[c0+64] = a1r; im[c0+64] = a1i;
    __syncthreads();
    {
        int i = (t & 127) + ((t >> 7) << 8);
        int j = i & 127;
        float wr = twr[j*2], wi = -twi[j*2];
        float ur = re[i], ui = im[i];
        float br = re[i+128], bi = im[i+128];
        float vr = br*wr - bi*wi, vi = br*wi + bi*wr;
        re[i] = ur + vr; im[i] = ui + vi;
        re[i+128] = ur - vr; im[i+128] = ui - vi;
    }
    __syncthreads();
    {
        float wr = twr[t], wi = -twi[t];
        float ur = re[t];
        float br = re[t+256], bi = im[t+256];
        float vr = br*wr - bi*wi;
        out0 = ur + vr;
        out1 = ur - vr;
    }
}

// ---------------- per-event scan with shuffle-FFT (5 barriers/frame) ----------------
__global__ __launch_bounds__(256) void k_event(const float2* __restrict__ Tscr, const float2* __restrict__ itfscr,
    const float* __restrict__ envsq, const float* __restrict__ noise, float* __restrict__ atoms)
{
    int ev = blockIdx.x; int t = threadIdx.x;
    __shared__ float twr[256], twi[256], re[512], im[512], envl[128];
    if (t < 128) envl[t] = envsq[ev*128 + t];
    {
        float ang = -6.283185307179586f * (float)t / 512.0f;
        float si, co;
        sincosf(ang, &si, &co);
        twr[t] = co; twi[t] = si;
    }
    float ham0 = 0.54f - 0.46f*cosf(6.283185307179586f*(float)t/512.0f);
    float ham1 = 0.54f - 0.46f*cosf(6.283185307179586f*(float)(t+256)/512.0f);
    __syncthreads();
    float imp0, imp1;
    fft_filt(noise[t], noise[t+256], itfscr + (size_t)ev*512, re, im, twr, twi, t, imp0, imp1);
    const float inv512 = 1.f/512.f;
    imp0 *= inv512; imp1 *= inv512;
    float carry0 = 0.f, carry1 = 0.f, accv = 0.f;
    #pragma unroll 1
    for (int f = 0; f < 128; ++f) {
        float e0, e1;
        {
            int tg = f*256 + t;
            float srcp = ((float)tg + 0.5f)*(1.0f/256.0f) - 0.5f;
            srcp = fminf(fmaxf(srcp, 0.f), 127.f);
            int i0 = (int)srcp; float fr = srcp - (float)i0;
            int i1 = i0 + 1; if (i1 > 127) i1 = 127;
            e0 = envl[i0]*(1.f-fr) + envl[i1]*fr;
        }
        {
            int tg = f*256 + 256 + t;
            e1 = 0.f;
            if (tg < NS) {
                float srcp = ((float)tg + 0.5f)*(1.0f/256.0f) - 0.5f;
                srcp = fminf(fmaxf(srcp, 0.f), 127.f);
                int i0 = (int)srcp; float fr = srcp - (float)i0;
                int i1 = i0 + 1; if (i1 > 127) i1 = 127;
                e1 = envl[i0]*(1.f-fr) + envl[i1]*fr;
            }
        }
        float nx0 = imp0*e0 + carry0;
        float nx1 = imp1*e1 + carry1;
        float o0, o1;
        fft_filt(nx0, nx1, Tscr + ((size_t)(ev*128 + f))*512, re, im, twr, twi, t, o0, o1);
        o0 *= inv512 * ham0;
        o1 *= inv512 * ham1;
        atoms[(size_t)ev*NS + f*256 + t] = o0 + accv;
        accv = o1; carry0 = o0; carry1 = o1;
    }
}

// ---------------- final = sum_a values[a]*atoms[a, t-idx[a]] ----------------
__global__ void k_gather(const float* __restrict__ atoms, const float* __restrict__ topv,
                         const int* __restrict__ topi, float* __restrict__ fin)
{
    int b = blockIdx.y;
    int t = blockIdx.x*256 + threadIdx.x;
    float s = 0.f;
    for (int a = 0; a < 32; ++a) {
        int ii = topi[b*32 + a];
        if (ii <= t) s += topv[b*32 + a] * atoms[(size_t)(b*32 + a)*NS + (t - ii)];
    }
    fin[b*NS + t] = s;
}

// ---------------- wet partials ----------------
__global__ __launch_bounds__(256) void k_wetpart(const float* __restrict__ fin, const float* __restrict__ ir,
                                                 float* __restrict__ wetp)
{
    int t0 = blockIdx.x*256;
    int by = blockIdx.y;
    int b = by >> 3, cg = by & 7;
    int tid = threadIdx.x;
    __shared__ float fs[256];
    __shared__ float irw[512];
    float wet = 0.f;
    int nch = t0/256 + 1;
    #pragma unroll 1
    for (int q = cg; q < nch; q += 8) {
        int c0 = q*256;
        __syncthreads();
        fs[tid] = fin[b*NS + c0 + tid];
        int dmin = t0 - c0 - 255;
        for (int qq = tid; qq < 511; qq += 256) {
            int dd = dmin + qq;
            irw[qq] = ((unsigned)dd < NS) ? ir[b*NS + dd] : 0.f;
        }
        __syncthreads();
        if (c0 < t0) {
            #pragma unroll 8
            for (int k = 0; k < 256; ++k) wet += fs[k]*irw[tid + 255 - k];
        } else {
            for (int k = 0; k <= tid; ++k) wet += fs[k]*irw[tid + 255 - k];
        }
    }
    wetp[(size_t)by*NS + t0 + tid] = wet;
}

// ---------------- out = m*sum(wet parts) + fin*(1-m) ----------------
__global__ __launch_bounds__(256) void k_wetsum(const float* __restrict__ fin, const float* __restrict__ wetp,
                                                const float* __restrict__ mval, float* __restrict__ out)
{
    int b = blockIdx.y;
    int t = blockIdx.x*256 + threadIdx.x;
    float w = 0.f;
    #pragma unroll
    for (int cg = 0; cg < 8; ++cg) w += wetp[(size_t)(b*8+cg)*NS + t];
    float m = mval[b];
    float fv = fin[b*NS + t];
    out[b*NS + t] = m*w + fv*(1.f - m);
}

extern "C" void kernel_launch(void* const* d_in, const int* in_sizes, int n_in,
                              void* d_out, int out_size, void* d_ws, size_t ws_size,
                              hipStream_t stream)
{
    (void)in_sizes; (void)n_in; (void)out_size; (void)ws_size;
    const float* x    = (const float*)d_in[0];
    const float* fbw  = (const float*)d_in[1];
    const float* dsw  = (const float*)d_in[2];
    const float* dsb  = (const float*)d_in[3];
    const float* dgw  = (const float*)d_in[4];
    const float* dgb  = (const float*)d_in[5];
    const float* dow  = (const float*)d_in[6];
    const float* dob  = (const float*)d_in[7];
    const float* dnw  = (const float*)d_in[8];
    const float* dnb  = (const float*)d_in[9];
    const float* elw  = (const float*)d_in[10];
    const float* elb  = (const float*)d_in[11];
    const float* ecw  = (const float*)d_in[12];
    const float* ecb  = (const float*)d_in[13];
    const float* efw  = (const float*)d_in[14];
    const float* efb  = (const float*)d_in[15];
    const float* tlw  = (const float*)d_in[16];
    const float* tlb  = (const float*)d_in[17];
    const float* tcw  = (const float*)d_in[18];
    const float* tcb  = (const float*)d_in[19];
    const float* tfw  = (const float*)d_in[20];
    const float* tfb  = (const float*)d_in[21];
    const float* iw   = (const float*)d_in[22];
    const float* ib   = (const float*)d_in[23];
    const float* iow  = (const float*)d_in[24];
    const float* iob  = (const float*)d_in[25];
    const float* rw   = (const float*)d_in[26];
    const float* rb   = (const float*)d_in[27];
    const float* row_ = (const float*)d_in[28];
    const float* rob  = (const float*)d_in[29];
    const float* mw   = (const float*)d_in[30];
    const float* mb   = (const float*)d_in[31];
    const float* mow  = (const float*)d_in[32];
    const float* mob  = (const float*)d_in[33];
    const float* rooms= (const float*)d_in[34];
    const float* noise= (const float*)d_in[35];

    float* ws   = (float*)d_ws;
    float* n0   = ws;                       // 16,777,216
    float* n1   = ws + 16777216;            // 16,777,216
    float* accb = ws + 33554432;            // 16,777,216
    float* wT   = ws + 50331648;            // 1,376,256
    float* woT  = ws + 51707904;            // 114,688
    float* wnT  = ws + 51822592;            // 114,688
    float* envsq= ws + 51937280;            // 16,384
    float* lat  = ws + 51953664;            // 16,384
    float* itfb = ws + 51970048;            // 65,792
    float* norms= ws + 52035840;            // 131,072
    float* topv = ws + 52166912;            // 128
    int*   topi = (int*)(ws + 52167040);    // 128
    float* agg  = ws + 52167168;            // 512
    float* probs= ws + 52167680;            // 32
    float* mval = ws + 52167712;            // 32
    float* irb  = ws + 52167744;            // 131,072
    float* fin  = ws + 52298816;            // 131,072
    // n0 layout after the stack (n0 dead: layer7 reads n0, writes n1):
    float* tfTt = n0;                        // 128*544*128 = 8,912,896
    float* atoms= n0 + 8912896;              // 4,194,304
    float* wetp = n0 + 13107200;             // 1,048,576
    float* Xg   = n0 + 14155776;             // 2,097,152  (total 16,252,928 < 16,777,216)
    float* wtu  = n1;                        // 393,216  (dead after convup3)
    float* wtf  = n1 + 393216;               // 208,896  (dead after tffin)
    float2* Tscr   = (float2*)n1;            // overwrites n1 after tffin
    float2* itfscr = (float2*)accb;          // accb dead after aggmax/latents

    float* out = (float*)d_out;

    k_wtrans<<<dim3((1376256+255)/256), dim3(256), 0, stream>>>(dsw, dgw, wT);
    k_wtrans2<<<dim3((114688+255)/256), dim3(256), 0, stream>>>(dow, dnw, woT, wnT);
    k_front<<<dim3(512,4), dim3(512), 0, stream>>>(x, fbw, n0);

    const int dil[7] = {1,3,9,27,81,243,1};
    float* cin = n0; float* cout = n1;
    for (int l = 0; l < 7; ++l) {
        k_layer<<<dim3(256,4), dim3(512), 0, stream>>>(
            cin, cout, accb, wT + l*98304,
            dsb + l*128, dgb + l*128,
            woT + l*16384, dob + l*128,
            wnT + l*16384, dnb + l*128,
            dil[l], l==0 ? 1 : 0);
        float* tmp = cin; cin = cout; cout = tmp;
    }
    k_norms<<<dim3(128,4), dim3(256), 0, stream>>>(accb, norms);
    k_topk<<<dim3(4), dim3(1024), 0, stream>>>(norms, topv, topi);
    k_latents<<<dim3(128), dim3(128), 0, stream>>>(accb, topi, lat);
    k_aggmax<<<dim3(512), dim3(256), 0, stream>>>(accb, agg);
    k_wtrans_up<<<dim3(1536), dim3(256), 0, stream>>>(ecw, tcw, tfw, wtu, wtf);
    k_convup3<<<dim3(128,2), dim3(512), 0, stream>>>(lat, elw, elb, ecb, efw, efb,
                                                     tlw, tlb, tcb, wtu, envsq, Xg);
    k_tffin<<<dim3(17,128), dim3(256), 0, stream>>>(Xg, wtf, tfb, tfTt);
    k_itf<<<dim3(128), dim3(128), 0, stream>>>(lat, iw, ib, iow, iob, itfb);
    k_roommix<<<dim3(4), dim3(128), 0, stream>>>(agg, rw, rb, row_, rob, mw, mb, mow, mob, probs, mval);
    k_ir<<<dim3(128,4), dim3(256), 0, stream>>>(probs, rooms, irb);
    k_tfprep<<<dim3(128,128), dim3(256), 0, stream>>>(tfTt, Tscr);
    k_itfprep<<<dim3(128), dim3(256), 0, stream>>>(itfb, itfscr);
    k_event<<<dim3(128), dim3(256), 0, stream>>>(Tscr, itfscr, envsq, noise, atoms);
    k_gather<<<dim3(128,4), dim3(256), 0, stream>>>(atoms, topv, topi, fin);
    k_wetpart<<<dim3(128,32), dim3(256), 0, stream>>>(fin, irb, wetp);
    k_wetsum<<<dim3(128,4), dim3(256), 0, stream>>>(fin, wetp, mval, out);
}